// Round 4
// baseline (1336.767 us; speedup 1.0000x reference)
//
#include <hip/hip_runtime.h>
#include <hip/hip_bf16.h>

#define N_NODES 100000
#define N_EDGES 1600000
#define F_IN    700
#define NKB0    22          // ceil(700/32)
#define HDIM    128
#define SCAN_B  256
#define NB_SCAN ((N_NODES + SCAN_B - 1) / SCAN_B)   // 391

typedef _Float16 half8 __attribute__((ext_vector_type(8)));
typedef _Float16 half4 __attribute__((ext_vector_type(4)));
typedef float floatx4 __attribute__((ext_vector_type(4)));

// async global->LDS, 16B per lane; dst slot = wave-uniform base + lane*16
__device__ __forceinline__ void cp16(const void* g, void* l) {
    __builtin_amdgcn_global_load_lds(
        (const __attribute__((address_space(1))) void*)g,
        (__attribute__((address_space(3))) void*)l, 16, 0, 0);
}

// unaligned-safe 16B load (A rows are only 4B-aligned: stride 700 floats)
__device__ __forceinline__ floatx4 ld4u(const float* p) {
    floatx4 v;
    __builtin_memcpy(&v, p, 16);
    return v;
}

// ---------------------------------------------------------------- CSR build
__global__ void count_edges(const int* __restrict__ graph, int* __restrict__ cnt) {
    int e = blockIdx.x * blockDim.x + threadIdx.x;
    if (e < N_EDGES) atomicAdd(&cnt[graph[2 * e + 1]], 1);
}

__global__ void scan1(const int* __restrict__ cnt, int* __restrict__ incl,
                      int* __restrict__ blk) {
    __shared__ int s[SCAN_B];
    int tid = threadIdx.x;
    int i = blockIdx.x * SCAN_B + tid;
    s[tid] = (i < N_NODES) ? cnt[i] : 0;
    __syncthreads();
    for (int off = 1; off < SCAN_B; off <<= 1) {
        int t = (tid >= off) ? s[tid - off] : 0;
        __syncthreads();
        s[tid] += t;
        __syncthreads();
    }
    if (i < N_NODES) incl[i] = s[tid];
    if (tid == SCAN_B - 1) blk[blockIdx.x] = s[tid];
}

__global__ void scan2(const int* __restrict__ blk, int* __restrict__ blkoff) {
    __shared__ int s[512];
    int tid = threadIdx.x;
    s[tid] = (tid < NB_SCAN) ? blk[tid] : 0;
    __syncthreads();
    for (int off = 1; off < 512; off <<= 1) {
        int t = (tid >= off) ? s[tid - off] : 0;
        __syncthreads();
        s[tid] += t;
        __syncthreads();
    }
    if (tid < NB_SCAN) blkoff[tid] = (tid == 0) ? 0 : s[tid - 1];
}

__global__ void scan3(const int* __restrict__ incl, const int* __restrict__ blkoff,
                      int* __restrict__ row_ptr) {
    int i = blockIdx.x * SCAN_B + threadIdx.x;
    if (i < N_NODES) {
        row_ptr[i + 1] = incl[i] + blkoff[i >> 8];
        if (i == 0) row_ptr[0] = 0;
    }
}

__global__ void fill_edges(const int* __restrict__ graph, const int* __restrict__ row_ptr,
                           int* __restrict__ cursor, int* __restrict__ esrc) {
    int e = blockIdx.x * blockDim.x + threadIdx.x;
    if (e < N_EDGES) {
        int src = graph[2 * e];
        int dst = graph[2 * e + 1];
        esrc[row_ptr[dst] + atomicAdd(&cursor[dst], 1)] = src;
    }
}

// ------------------- weight packs: tile-major, XOR-swizzled LDS image (fp16)
// out[((kb*256 + r)*4 + cc)*8 + e] = W[k = kb*32 + (cc^((r>>1)&3))*8 + e][col r]
// rows 0..127 = Wneigh cols, 128..255 = Wself cols; per-kb halves are 4096-half
// contiguous (8KB), so an N-split block can DMA just its half.
__global__ void build_wtp0(const float* __restrict__ Wn, const float* __restrict__ Ws,
                           _Float16* __restrict__ out) {
    int q = blockIdx.x * blockDim.x + threadIdx.x;
    if (q >= NKB0 * 256 * 4) return;
    int kb = q >> 10;
    int r  = (q >> 2) & 255;
    int cc = q & 3;
    int k0 = kb * 32 + (cc ^ ((r >> 1) & 3)) * 8;
    half8 v;
    #pragma unroll
    for (int e = 0; e < 8; e++) {
        int k = k0 + e;
        float f = 0.0f;
        if (k < F_IN) f = (r < 128) ? Wn[k * 128 + r] : Ws[k * 128 + (r - 128)];
        v[e] = (_Float16)f;
    }
    *(half8*)&out[(size_t)q * 8] = v;
}

__global__ void build_wtpl(const float* __restrict__ Wn, const float* __restrict__ Ws,
                           _Float16* __restrict__ out) {
    int q = blockIdx.x * blockDim.x + threadIdx.x;
    if (q >= 3 * 4 * 256 * 4) return;
    int l = q >> 12;
    int rem = q & 4095;
    int kb = rem >> 10;
    int r  = (rem >> 2) & 255;
    int cc = rem & 3;
    int k0 = kb * 32 + (cc ^ ((r >> 1) & 3)) * 8;
    half8 v;
    #pragma unroll
    for (int e = 0; e < 8; e++) {
        int k = k0 + e;
        float f = (r < 128) ? Wn[l * 16384 + k * 128 + r]
                            : Ws[l * 16384 + k * 128 + (r - 128)];
        v[e] = (_Float16)f;
    }
    *(half8*)&out[(size_t)q * 8] = v;
}

// --------- layer-0 N-split GEMM, reg-staged fp16 A (T14):
// Each thread: 4x global dwordx4 (16 fp32) -> cvt fp16 -> 2x ds_write_b128
// into the same XOR-swizzled [128][32] fp16 image gemm16 uses; B reg-staged
// from the pre-swizzled pack. All loads compiler-tracked (exact auto-vmcnt
// before use); barriers are raw lgkmcnt(0)+s_barrier (no vmcnt drain), so
// next-tile loads stay in flight across them. LDS 2x16KB = 32KB total.
// Stage-write addrs are linear per instr (lane t -> byte 16t): no conflicts.
__global__ __launch_bounds__(256) void gemm0_rs(
    const float* __restrict__ A, int M, int K,
    const _Float16* __restrict__ Wtp, const float* __restrict__ bias,
    const float* __restrict__ zbuf,
    _Float16* __restrict__ Cn, float* __restrict__ Cs) {
    __shared__ _Float16 sbuf[2][8192];   // per buf: A halves [0,4096), B [4096,8192)

    int tid = threadIdx.x;
    int wave = tid >> 6, lane = tid & 63;
    int lm = lane & 15, quad = lane >> 4;
    int wm = wave >> 1, wn = wave & 1;      // 2x2 waves: 64 rows x 64 cols each
    int bx = blockIdx.x;
    long row0 = (long)(bx >> 1) * 128;
    int nh = bx & 1;

    // A-stage decomposition: thread t writes slot s=t&3 of rows t>>2 and 64+(t>>2)
    // slot s of row r holds chunk cc = s ^ ((r>>1)&3)  (reader: ch = quad ^ ((row>>1)&3))
    int ra1 = tid >> 2, s4 = tid & 3;
    int ra2 = 64 + ra1;
    int cc1 = s4 ^ ((ra1 >> 1) & 3);
    int cc2 = s4 ^ ((ra2 >> 1) & 3);
    long ga1 = row0 + ra1; if (ga1 >= M) ga1 = 0;   // clamp; outputs discarded
    long ga2 = row0 + ra2; if (ga2 >= M) ga2 = 0;
    const float* arow1 = A + ga1 * (long)K;
    const float* arow2 = A + ga2 * (long)K;
    const _Float16* wbase = Wtp + nh * 4096;

    floatx4 R[4];        // staged A fp32 (16 floats) for the in-flight tile
    half8 Bv[2];         // staged B (32B) for the in-flight tile

    auto loadA = [&](int kb) {
        int k1 = kb * 32 + cc1 * 8;
        int k2 = kb * 32 + cc2 * 8;
        R[0] = (k1 + 4 <= K) ? ld4u(arow1 + k1)     : ld4u(zbuf);
        R[1] = (k1 + 8 <= K) ? ld4u(arow1 + k1 + 4) : ld4u(zbuf);
        R[2] = (k2 + 4 <= K) ? ld4u(arow2 + k2)     : ld4u(zbuf);
        R[3] = (k2 + 8 <= K) ? ld4u(arow2 + k2 + 4) : ld4u(zbuf);
    };
    auto loadB = [&](int kb) {
        const _Float16* wsrc = wbase + (size_t)kb * 8192;
        Bv[0] = *(const half8*)(wsrc + tid * 8);
        Bv[1] = *(const half8*)(wsrc + 2048 + tid * 8);
    };
    auto writeAB = [&](_Float16* buf) {
        half8 h1, h2;
        #pragma unroll
        for (int e = 0; e < 4; e++) {
            h1[e]     = (_Float16)R[0][e];
            h1[e + 4] = (_Float16)R[1][e];
            h2[e]     = (_Float16)R[2][e];
            h2[e + 4] = (_Float16)R[3][e];
        }
        *(half8*)&buf[ra1 * 32 + s4 * 8] = h1;
        *(half8*)&buf[ra2 * 32 + s4 * 8] = h2;
        *(half8*)&buf[4096 + tid * 8]        = Bv[0];
        *(half8*)&buf[4096 + 2048 + tid * 8] = Bv[1];
    };

    floatx4 acc[4][4] = {};

    // prologue: tile 0 staged to LDS; tile 1 loads in flight across the barrier
    loadA(0); loadB(0);
    writeAB(sbuf[0]);
    loadA(1); loadB(1);
    asm volatile("s_waitcnt lgkmcnt(0)\n\ts_barrier" ::: "memory");

    #pragma unroll 2
    for (int kb = 0; kb < NKB0; kb++) {
        int p = kb & 1;
        const _Float16* bp = sbuf[p];

        half8 af[4];
        #pragma unroll
        for (int i = 0; i < 4; i++) {
            int row = wm * 64 + i * 16 + lm;
            int ch = quad ^ ((row >> 1) & 3);
            af[i] = *(const half8*)&bp[row * 32 + ch * 8];
        }
        #pragma unroll
        for (int j = 0; j < 4; j++) {
            int brow = wn * 64 + j * 16 + lm;
            int ch = quad ^ ((brow >> 1) & 3);
            half8 bf = *(const half8*)&bp[4096 + brow * 32 + ch * 8];
            #pragma unroll
            for (int i = 0; i < 4; i++)
                acc[i][j] = __builtin_amdgcn_mfma_f32_16x16x32_f16(af[i], bf, acc[i][j], 0, 0, 0);
        }

        if (kb + 1 < NKB0) {
            writeAB(sbuf[p ^ 1]);            // auto-waits tile kb+1's loads only
            if (kb + 2 < NKB0) { loadA(kb + 2); loadB(kb + 2); }  // fly over barrier
            asm volatile("s_waitcnt lgkmcnt(0)\n\ts_barrier" ::: "memory");
        }
    }

    #pragma unroll
    for (int i = 0; i < 4; i++) {
        long r0 = row0 + wm * 64 + i * 16 + quad * 4;
        #pragma unroll
        for (int j = 0; j < 4; j++) {
            int c = wn * 64 + j * 16 + lm;              // output channel 0..127
            if (nh) {
                float badd = bias[c];
                #pragma unroll
                for (int rr = 0; rr < 4; rr++) {
                    long r = r0 + rr;
                    if (r < M) Cs[r * HDIM + c] = acc[i][j][rr] + badd;
                }
            } else {
                #pragma unroll
                for (int rr = 0; rr < 4; rr++) {
                    long r = r0 + rr;
                    if (r < M) Cn[r * HDIM + c] = (_Float16)acc[i][j][rr];
                }
            }
        }
    }
}

// -------------------- K=128 N-split GEMM: fp16 A; counted-vmcnt pipeline
__global__ __launch_bounds__(256) void gemm16_ns(
    const _Float16* __restrict__ A, int M,
    const _Float16* __restrict__ Wtp, const float* __restrict__ bias,
    _Float16* __restrict__ Cn, float* __restrict__ Cs) {
    __shared__ _Float16 sbuf[2][8192];   // A 4096 halves + B 4096 halves

    int tid = threadIdx.x;
    int wave = tid >> 6, lane = tid & 63;
    int lm = lane & 15, quad = lane >> 4;
    int wm = wave >> 1, wn = wave & 1;
    int bx = blockIdx.x;
    long row0 = (long)(bx >> 1) * 128;
    int nh = bx & 1;

    floatx4 acc[4][4] = {};

    auto stage = [&](int kb, _Float16* buf) {
        #pragma unroll
        for (int pass = 0; pass < 2; pass++) {
            int q = pass * 256 + tid;
            int r = q >> 2, cc = q & 3;
            int ccg = cc ^ ((r >> 1) & 3);
            long grow = row0 + r;
            if (grow >= M) grow = 0;        // clamp: uniform load count per wave
            cp16(A + grow * (long)HDIM + kb * 32 + ccg * 8,
                 buf + pass * 2048 + wave * 512);
        }
        const _Float16* wsrc = Wtp + (size_t)kb * 8192 + nh * 4096;
        #pragma unroll
        for (int pass = 0; pass < 2; pass++) {
            cp16(wsrc + (size_t)(pass * 256 + tid) * 8,
                 buf + 4096 + pass * 2048 + wave * 512);
        }
    };

    stage(0, sbuf[0]);   // 4 loads in flight

    for (int kb = 0; kb < 4; kb++) {
        int p = kb & 1;
        if (kb + 1 < 4) {
            stage(kb + 1, sbuf[p ^ 1]);
            asm volatile("s_waitcnt vmcnt(4)\n\ts_barrier" ::: "memory");
        } else {
            asm volatile("s_waitcnt vmcnt(0)\n\ts_barrier" ::: "memory");
        }

        const _Float16* bp = sbuf[p];
        half8 af[4];
        #pragma unroll
        for (int i = 0; i < 4; i++) {
            int row = wm * 64 + i * 16 + lm;
            int ch = quad ^ ((row >> 1) & 3);
            af[i] = *(const half8*)&bp[row * 32 + ch * 8];
        }
        #pragma unroll
        for (int j = 0; j < 4; j++) {
            int brow = wn * 64 + j * 16 + lm;
            int ch = quad ^ ((brow >> 1) & 3);
            half8 bf = *(const half8*)&bp[4096 + brow * 32 + ch * 8];
            #pragma unroll
            for (int i = 0; i < 4; i++)
                acc[i][j] = __builtin_amdgcn_mfma_f32_16x16x32_f16(af[i], bf, acc[i][j], 0, 0, 0);
        }
        asm volatile("s_waitcnt lgkmcnt(0)\n\ts_barrier" ::: "memory");
    }

    #pragma unroll
    for (int i = 0; i < 4; i++) {
        long r0 = row0 + wm * 64 + i * 16 + quad * 4;
        #pragma unroll
        for (int j = 0; j < 4; j++) {
            int c = wn * 64 + j * 16 + lm;
            if (nh) {
                float badd = bias[c];
                #pragma unroll
                for (int rr = 0; rr < 4; rr++) {
                    long r = r0 + rr;
                    if (r < M) Cs[r * HDIM + c] = acc[i][j][rr] + badd;
                }
            } else {
                #pragma unroll
                for (int rr = 0; rr < 4; rr++) {
                    long r = r0 + rr;
                    if (r < M) Cn[r * HDIM + c] = (_Float16)acc[i][j][rr];
                }
            }
        }
    }
}

// ------------------------------------------------------------- aggregation
__global__ __launch_bounds__(256) void aggregate_w(
    const _Float16* __restrict__ hn, const int* __restrict__ row_ptr,
    const int* __restrict__ esrc, float* __restrict__ pre) {
    int wave = threadIdx.x >> 6, lane = threadIdx.x & 63;
    int n = blockIdx.x * 4 + wave;
    if (n >= N_NODES) return;
    int start = row_ptr[n], end = row_ptr[n + 1];
    int eg = lane >> 4;            // edge slot 0..3
    int c8 = (lane & 15) * 8;      // channel group

    float acc[8] = {};
    for (int base = start; base < end; base += 16) {
        #pragma unroll
        for (int u = 0; u < 4; u++) {
            int e = base + u * 4 + eg;
            if (e < end) {
                int s = esrc[e];
                half8 v = *(const half8*)&hn[(size_t)s * HDIM + c8];
                #pragma unroll
                for (int i = 0; i < 8; i++) acc[i] += (float)v[i];
            }
        }
    }
    #pragma unroll
    for (int i = 0; i < 8; i++) {
        acc[i] += __shfl_xor(acc[i], 16, 64);
        acc[i] += __shfl_xor(acc[i], 32, 64);
    }
    if (eg == 0) {
        float rd = 1.0f / (float)max(end - start, 1);
        size_t off = (size_t)n * HDIM + c8;
        float4 p0 = *(float4*)&pre[off];
        float4 p1 = *(float4*)&pre[off + 4];
        p0.x += acc[0] * rd; p0.y += acc[1] * rd;
        p0.z += acc[2] * rd; p0.w += acc[3] * rd;
        p1.x += acc[4] * rd; p1.y += acc[5] * rd;
        p1.z += acc[6] * rd; p1.w += acc[7] * rd;
        *(float4*)&pre[off]     = p0;
        *(float4*)&pre[off + 4] = p1;
    }
}

// --------------------------------------------------------------- batch norm
__global__ void bn_stats(const float* __restrict__ P, float* __restrict__ gsum,
                         float* __restrict__ gsumsq, int M, int C) {
    int tid = threadIdx.x;
    int c = tid % C;
    int rpb = 256 / C;
    float s = 0.0f, s2 = 0.0f;
    for (int r = blockIdx.x * rpb + tid / C; r < M; r += gridDim.x * rpb) {
        float v = P[(size_t)r * C + c];
        s += v; s2 += v * v;
    }
    __shared__ float ss[256], ss2[256];
    ss[tid] = s; ss2[tid] = s2;
    __syncthreads();
    for (int off = 128; off >= C; off >>= 1) {
        if (tid < off) { ss[tid] += ss[tid + off]; ss2[tid] += ss2[tid + off]; }
        __syncthreads();
    }
    if (tid < C) {
        atomicAdd(&gsum[tid], ss[tid]);
        atomicAdd(&gsumsq[tid], ss2[tid]);
    }
}

// h16 = fp16(relu(P*scale+shift [+ res16])), scale/shift derived per-block
__global__ void bn_apply16(const float* __restrict__ P, const _Float16* __restrict__ res16,
                           _Float16* __restrict__ out16,
                           const float* __restrict__ gsum, const float* __restrict__ gsumsq,
                           const float* __restrict__ gamma, const float* __restrict__ beta,
                           int M, int total4, int Cdiv4) {
    __shared__ float ssc[HDIM], ssh[HDIM];
    int tid = threadIdx.x;
    int C = Cdiv4 * 4;
    if (tid < C) {
        float mean = gsum[tid] / (float)M;
        float var = gsumsq[tid] / (float)M - mean * mean;
        float sc = rsqrtf(var + 1e-5f) * gamma[tid];
        ssc[tid] = sc;
        ssh[tid] = beta[tid] - mean * sc;
    }
    __syncthreads();
    for (int f = blockIdx.x * blockDim.x + tid; f < total4;
         f += gridDim.x * blockDim.x) {
        int c4 = (f % Cdiv4) * 4;
        float4 v = ((const float4*)P)[f];
        v.x = v.x * ssc[c4 + 0] + ssh[c4 + 0];
        v.y = v.y * ssc[c4 + 1] + ssh[c4 + 1];
        v.z = v.z * ssc[c4 + 2] + ssh[c4 + 2];
        v.w = v.w * ssc[c4 + 3] + ssh[c4 + 3];
        if (res16) {
            half4 rv = *(const half4*)&res16[(size_t)f * 4];
            v.x += (float)rv[0]; v.y += (float)rv[1];
            v.z += (float)rv[2]; v.w += (float)rv[3];
        }
        half4 h;
        h[0] = (_Float16)fmaxf(v.x, 0.0f); h[1] = (_Float16)fmaxf(v.y, 0.0f);
        h[2] = (_Float16)fmaxf(v.z, 0.0f); h[3] = (_Float16)fmaxf(v.w, 0.0f);
        *(half4*)&out16[(size_t)f * 4] = h;
    }
}

// --------------------------------------------------------------- MLP head
__global__ __launch_bounds__(256) void mlp_gemm(const _Float16* __restrict__ H,
                                                const float* __restrict__ W1,
                                                const float* __restrict__ b1,
                                                float* __restrict__ Z, int M) {
    __shared__ float hs[64 * 132];
    __shared__ float ws[128 * 64];
    int tid = threadIdx.x;
    int tx = tid & 15;
    int ty = tid >> 4;
    int row0 = blockIdx.x * 64;

    #pragma unroll
    for (int t = 0; t < 8; t++) {
        int f = tid + t * 256;
        int r = f >> 4, c4 = (f & 15) * 4;
        *(float4*)&ws[r * 64 + c4] = *(const float4*)&W1[r * 64 + c4];
    }
    #pragma unroll
    for (int t = 0; t < 4; t++) {
        int f = tid + t * 256;
        int r = f >> 4, c8 = (f & 15) * 8;
        int gr = row0 + r;
        if (gr < M) {
            half8 hv = *(const half8*)&H[(size_t)gr * HDIM + c8];
            #pragma unroll
            for (int i = 0; i < 8; i++) hs[r * 132 + c8 + i] = (float)hv[i];
        } else {
            #pragma unroll
            for (int i = 0; i < 8; i++) hs[r * 132 + c8 + i] = 0.0f;
        }
    }
    __syncthreads();

    float acc[4][4] = {};
    for (int k = 0; k < 128; k++) {
        float a[4];
        #pragma unroll
        for (int i = 0; i < 4; i++) a[i] = hs[(ty * 4 + i) * 132 + k];
        float4 b4 = *(const float4*)&ws[k * 64 + tx * 4];
        #pragma unroll
        for (int i = 0; i < 4; i++) {
            acc[i][0] += a[i] * b4.x; acc[i][1] += a[i] * b4.y;
            acc[i][2] += a[i] * b4.z; acc[i][3] += a[i] * b4.w;
        }
    }
    float4 bb = *(const float4*)&b1[tx * 4];
    #pragma unroll
    for (int i = 0; i < 4; i++) {
        int r = row0 + ty * 4 + i;
        if (r < M) {
            float4 v = {acc[i][0] + bb.x, acc[i][1] + bb.y,
                        acc[i][2] + bb.z, acc[i][3] + bb.w};
            *(float4*)&Z[(size_t)r * 64 + tx * 4] = v;
        }
    }
}

// out[n] = relu(bn(Z[n,:])) . W2 + b2  — BN finalize+apply fused into the dot
__global__ void final_out(const float* __restrict__ Z,
                          const float* __restrict__ gsum, const float* __restrict__ gsumsq,
                          const float* __restrict__ gamma, const float* __restrict__ beta,
                          const float* __restrict__ W2, const float* __restrict__ b2,
                          float* __restrict__ out, int M) {
    __shared__ float ssc[64], ssh[64], sw[64];
    int tid = threadIdx.x;
    if (tid < 64) {
        float mean = gsum[tid] / (float)M;
        float var = gsumsq[tid] / (float)M - mean * mean;
        float sc = rsqrtf(var + 1e-5f) * gamma[tid];
        ssc[tid] = sc;
        ssh[tid] = beta[tid] - mean * sc;
        sw[tid] = W2[tid];
    }
    __syncthreads();
    int n = blockIdx.x * 4 + (tid >> 6);
    int lane = tid & 63;
    if (n >= N_NODES) return;
    float z = Z[(size_t)n * 64 + lane] * ssc[lane] + ssh[lane];
    z = fmaxf(z, 0.0f);
    float v = z * sw[lane];
    #pragma unroll
    for (int off = 32; off >= 1; off >>= 1) v += __shfl_down(v, off, 64);
    if (lane == 0) out[n] = v + b2[0];
}

// ------------------------------------------------------------------ driver
extern "C" void kernel_launch(void* const* d_in, const int* in_sizes, int n_in,
                              void* d_out, int out_size, void* d_ws, size_t ws_size,
                              hipStream_t stream) {
    const float* X       = (const float*)d_in[0];
    const int*   graph   = (const int*)d_in[1];
    const float* Wself0  = (const float*)d_in[2];
    const float* Wneigh0 = (const float*)d_in[3];
    const float* b0      = (const float*)d_in[4];
    const float* Wself   = (const float*)d_in[5];
    const float* Wneigh  = (const float*)d_in[6];
    const float* bvec    = (const float*)d_in[7];
    const float* bn_g    = (const float*)d_in[8];
    const float* bn_b    = (const float*)d_in[9];
    const float* W1      = (const float*)d_in[10];
    const float* b1      = (const float*)d_in[11];
    const float* bng1    = (const float*)d_in[12];
    const float* bnb1    = (const float*)d_in[13];
    const float* W2      = (const float*)d_in[14];
    const float* b2      = (const float*)d_in[15];
    float* out = (float*)d_out;

    size_t off = 0;
    auto alloc = [&](size_t bytes) {
        void* p = (char*)d_ws + off;
        off += (bytes + 255) & ~(size_t)255;
        return p;
    };
    int* cnt     = (int*)alloc(N_NODES * 4);
    int* cursor  = (int*)alloc(N_NODES * 4);
    int* row_ptr = (int*)alloc((N_NODES + 1) * 4);
    int* incl    = (int*)alloc(N_NODES * 4);
    int* blk     = (int*)alloc(NB_SCAN * 4);
    int* blkoff  = (int*)alloc(NB_SCAN * 4);
    int* esrc    = (int*)alloc((size_t)N_EDGES * 4);
    float*    pre   = (float*)alloc((size_t)N_NODES * HDIM * 4);    // 51.2 MB
    _Float16* h16A  = (_Float16*)alloc((size_t)N_NODES * HDIM * 2); // 25.6 MB
    _Float16* h16B  = (_Float16*)alloc((size_t)N_NODES * HDIM * 2);
    _Float16* hn16  = (_Float16*)alloc((size_t)N_NODES * HDIM * 2);
    float*    Z     = (float*)alloc((size_t)N_NODES * 64 * 4);
    _Float16* Wtp0  = (_Float16*)alloc((size_t)NKB0 * 8192 * 2);
    _Float16* Wtpl  = (_Float16*)alloc((size_t)3 * 4 * 8192 * 2);
    float*    zbuf  = (float*)alloc(256);
    float* stats = (float*)alloc(256 * 4);
    float* gsum = stats, *gsumsq = stats + 128;

    const int EB = (N_EDGES + 255) / 256;
    const int GB = ((N_NODES + 127) / 128) * 2;   // 1564 (M-tiles x 2 N-halves)
    const int AGB = (N_NODES + 3) / 4;            // 25000

    // CSR build
    hipMemsetAsync(cnt, 0, N_NODES * 4, stream);
    hipMemsetAsync(cursor, 0, N_NODES * 4, stream);
    hipMemsetAsync(zbuf, 0, 256, stream);
    count_edges<<<EB, 256, 0, stream>>>(graph, cnt);
    scan1<<<NB_SCAN, SCAN_B, 0, stream>>>(cnt, incl, blk);
    scan2<<<1, 512, 0, stream>>>(blk, blkoff);
    scan3<<<NB_SCAN, SCAN_B, 0, stream>>>(incl, blkoff, row_ptr);
    fill_edges<<<EB, 256, 0, stream>>>(graph, row_ptr, cursor, esrc);

    // weight packs
    build_wtp0<<<(NKB0 * 1024 + 255) / 256, 256, 0, stream>>>(Wneigh0, Wself0, Wtp0);
    build_wtpl<<<(3 * 4096 + 255) / 256, 256, 0, stream>>>(Wneigh, Wself, Wtpl);

    _Float16* hc = h16A;
    _Float16* hx = h16B;

    // ---- layer 0 (K = 700, fp32 A reg-staged -> fp16 LDS, N-split)
    gemm0_rs<<<GB, 256, 0, stream>>>(X, N_NODES, F_IN, Wtp0, b0, zbuf, hn16, pre);
    aggregate_w<<<AGB, 256, 0, stream>>>(hn16, row_ptr, esrc, pre);
    hipMemsetAsync(stats, 0, 256 * 4, stream);
    bn_stats<<<512, 256, 0, stream>>>(pre, gsum, gsumsq, N_NODES, 128);
    bn_apply16<<<1024, 256, 0, stream>>>(pre, nullptr, hc, gsum, gsumsq,
                                         bn_g, bn_b, N_NODES,
                                         N_NODES * HDIM / 4, HDIM / 4);

    // ---- layers 1..3 (K = 128, residual in fp16, N-split)
    for (int l = 0; l < 3; l++) {
        gemm16_ns<<<GB, 256, 0, stream>>>(hc, N_NODES, Wtpl + (size_t)l * 32768,
                                          bvec + l * HDIM, hn16, pre);
        aggregate_w<<<AGB, 256, 0, stream>>>(hn16, row_ptr, esrc, pre);
        hipMemsetAsync(stats, 0, 256 * 4, stream);
        bn_stats<<<512, 256, 0, stream>>>(pre, gsum, gsumsq, N_NODES, 128);
        bn_apply16<<<1024, 256, 0, stream>>>(pre, hc, hx, gsum, gsumsq,
                                             bn_g + (l + 1) * HDIM,
                                             bn_b + (l + 1) * HDIM, N_NODES,
                                             N_NODES * HDIM / 4, HDIM / 4);
        _Float16* t = hc; hc = hx; hx = t;
    }

    // ---- MLP head (BN finalize+apply+ReLU fused into final_out)
    mlp_gemm<<<(N_NODES + 63) / 64, 256, 0, stream>>>(hc, W1, b1, Z, N_NODES);
    hipMemsetAsync(stats, 0, 256 * 4, stream);
    bn_stats<<<512, 256, 0, stream>>>(Z, gsum, gsumsq, N_NODES, 64);
    final_out<<<AGB, 256, 0, stream>>>(Z, gsum, gsumsq, bng1, bnb1, W2, b2,
                                       out, N_NODES);
}

// Round 5
// 1208.523 us; speedup vs baseline: 1.1061x; 1.1061x over previous
//
#include <hip/hip_runtime.h>
#include <hip/hip_bf16.h>

#define N_NODES 100000
#define N_EDGES 1600000
#define F_IN    700
#define NKB0    22          // ceil(700/32)
#define HDIM    128
#define SCAN_B  256
#define NB_SCAN ((N_NODES + SCAN_B - 1) / SCAN_B)   // 391
#define NSHARD  64          // stats shards: stats[NSHARD][256] (sum | sumsq@+128)

typedef _Float16 half8 __attribute__((ext_vector_type(8)));
typedef _Float16 half4 __attribute__((ext_vector_type(4)));
typedef float floatx4 __attribute__((ext_vector_type(4)));

// async global->LDS, 16B per lane; dst slot = wave-uniform base + lane*16
__device__ __forceinline__ void cp16(const void* g, void* l) {
    __builtin_amdgcn_global_load_lds(
        (const __attribute__((address_space(1))) void*)g,
        (__attribute__((address_space(3))) void*)l, 16, 0, 0);
}

// ---------------------------------------------------------------- CSR build
__global__ void count_edges(const int* __restrict__ graph, int* __restrict__ cnt) {
    int e = blockIdx.x * blockDim.x + threadIdx.x;
    if (e < N_EDGES) atomicAdd(&cnt[graph[2 * e + 1]], 1);
}

__global__ void scan1(const int* __restrict__ cnt, int* __restrict__ incl,
                      int* __restrict__ blk) {
    __shared__ int s[SCAN_B];
    int tid = threadIdx.x;
    int i = blockIdx.x * SCAN_B + tid;
    s[tid] = (i < N_NODES) ? cnt[i] : 0;
    __syncthreads();
    for (int off = 1; off < SCAN_B; off <<= 1) {
        int t = (tid >= off) ? s[tid - off] : 0;
        __syncthreads();
        s[tid] += t;
        __syncthreads();
    }
    if (i < N_NODES) incl[i] = s[tid];
    if (tid == SCAN_B - 1) blk[blockIdx.x] = s[tid];
}

__global__ void scan2(const int* __restrict__ blk, int* __restrict__ blkoff) {
    __shared__ int s[512];
    int tid = threadIdx.x;
    s[tid] = (tid < NB_SCAN) ? blk[tid] : 0;
    __syncthreads();
    for (int off = 1; off < 512; off <<= 1) {
        int t = (tid >= off) ? s[tid - off] : 0;
        __syncthreads();
        s[tid] += t;
        __syncthreads();
    }
    if (tid < NB_SCAN) blkoff[tid] = (tid == 0) ? 0 : s[tid - 1];
}

__global__ void scan3(const int* __restrict__ incl, const int* __restrict__ blkoff,
                      int* __restrict__ row_ptr) {
    int i = blockIdx.x * SCAN_B + threadIdx.x;
    if (i < N_NODES) {
        row_ptr[i + 1] = incl[i] + blkoff[i >> 8];
        if (i == 0) row_ptr[0] = 0;
    }
}

__global__ void fill_edges(const int* __restrict__ graph, const int* __restrict__ row_ptr,
                           int* __restrict__ cursor, int* __restrict__ esrc) {
    int e = blockIdx.x * blockDim.x + threadIdx.x;
    if (e < N_EDGES) {
        int src = graph[2 * e];
        int dst = graph[2 * e + 1];
        esrc[row_ptr[dst] + atomicAdd(&cursor[dst], 1)] = src;
    }
}

// ------------------- weight packs: tile-major, XOR-swizzled LDS image (fp16)
// out[((kb*256 + r)*4 + cc)*8 + e] = W[k = kb*32 + (cc^((r>>1)&3))*8 + e][col r]
// rows 0..127 = Wneigh cols, 128..255 = Wself cols; per-kb halves are 4096-half
// contiguous (8KB), so an N-split block can DMA just its half.
__global__ void build_wtp0(const float* __restrict__ Wn, const float* __restrict__ Ws,
                           _Float16* __restrict__ out) {
    int q = blockIdx.x * blockDim.x + threadIdx.x;
    if (q >= NKB0 * 256 * 4) return;
    int kb = q >> 10;
    int r  = (q >> 2) & 255;
    int cc = q & 3;
    int k0 = kb * 32 + (cc ^ ((r >> 1) & 3)) * 8;
    half8 v;
    #pragma unroll
    for (int e = 0; e < 8; e++) {
        int k = k0 + e;
        float f = 0.0f;
        if (k < F_IN) f = (r < 128) ? Wn[k * 128 + r] : Ws[k * 128 + (r - 128)];
        v[e] = (_Float16)f;
    }
    *(half8*)&out[(size_t)q * 8] = v;
}

__global__ void build_wtpl(const float* __restrict__ Wn, const float* __restrict__ Ws,
                           _Float16* __restrict__ out) {
    int q = blockIdx.x * blockDim.x + threadIdx.x;
    if (q >= 3 * 4 * 256 * 4) return;
    int l = q >> 12;
    int rem = q & 4095;
    int kb = rem >> 10;
    int r  = (rem >> 2) & 255;
    int cc = rem & 3;
    int k0 = kb * 32 + (cc ^ ((r >> 1) & 3)) * 8;
    half8 v;
    #pragma unroll
    for (int e = 0; e < 8; e++) {
        int k = k0 + e;
        float f = (r < 128) ? Wn[l * 16384 + k * 128 + r]
                            : Ws[l * 16384 + k * 128 + (r - 128)];
        v[e] = (_Float16)f;
    }
    *(half8*)&out[(size_t)q * 8] = v;
}

// ----------------- layer-0 N-split GEMM: fp32 A staged raw, cvt at frag read
// T4 counted-vmcnt pipeline (R1, best-known): stage(kb+1)'s 6 loads stay in
// flight across both barriers; waits are vmcnt(6), never 0 in the main loop.
__global__ __launch_bounds__(256) void gemm0_ns(
    const float* __restrict__ A, int M, int K,
    const _Float16* __restrict__ Wtp, const float* __restrict__ bias,
    const float* __restrict__ zbuf,
    _Float16* __restrict__ Cn, float* __restrict__ Cs) {
    __shared__ char sbuf[2][24576];

    int tid = threadIdx.x;
    int wave = tid >> 6, lane = tid & 63;
    int lm = lane & 15, quad = lane >> 4;
    int wm = wave >> 1, wn = wave & 1;      // 2x2 waves: 64 rows x 64 cols each
    int bx = blockIdx.x;
    long row0 = (long)(bx >> 1) * 128;
    int nh = bx & 1;

    floatx4 acc[4][4] = {};

    auto stage = [&](int kb, char* buf) {
        // A: 1024 16B chunks (4 floats), XOR-swizzled slot cc holds chunk cc^(r&7)
        #pragma unroll
        for (int pass = 0; pass < 4; pass++) {
            int q = pass * 256 + tid;
            int r = q >> 3, cc = q & 7;
            int ccg = cc ^ (r & 7);
            long grow = row0 + r;
            if (grow >= M) grow = 0;        // clamp: uniform load count per wave
            int gk = kb * 32 + ccg * 4;
            const float* src = (gk + 4 <= K) ? (A + grow * (long)K + gk) : zbuf;
            cp16(src, buf + pass * 4096 + wave * 1024);
        }
        // B half: 512 chunks, linear (pre-swizzled at pack time)
        const _Float16* wsrc = Wtp + (size_t)kb * 8192 + nh * 4096;
        #pragma unroll
        for (int pass = 0; pass < 2; pass++) {
            cp16(wsrc + (size_t)(pass * 256 + tid) * 8,
                 buf + 16384 + pass * 4096 + wave * 1024);
        }
    };

    stage(0, sbuf[0]);   // 6 loads in flight; waited inside the loop

    for (int kb = 0; kb < NKB0; kb++) {
        int p = kb & 1;
        if (kb + 1 < NKB0) {
            stage(kb + 1, sbuf[p ^ 1]);
            // wait for tile kb's 6 loads; tile kb+1's 6 stay in flight
            asm volatile("s_waitcnt vmcnt(6)\n\ts_barrier" ::: "memory");
        } else {
            asm volatile("s_waitcnt vmcnt(0)\n\ts_barrier" ::: "memory");
        }

        const float* Af = (const float*)sbuf[p];
        const _Float16* Bf = (const _Float16*)(sbuf[p] + 16384);
        half8 af[4];
        #pragma unroll
        for (int i = 0; i < 4; i++) {
            int row = wm * 64 + i * 16 + lm;
            int c0 = (quad * 2) ^ (row & 7);
            int c1 = (quad * 2 + 1) ^ (row & 7);
            floatx4 f0 = *(const floatx4*)&Af[row * 32 + c0 * 4];
            floatx4 f1 = *(const floatx4*)&Af[row * 32 + c1 * 4];
            af[i][0] = (_Float16)f0[0]; af[i][1] = (_Float16)f0[1];
            af[i][2] = (_Float16)f0[2]; af[i][3] = (_Float16)f0[3];
            af[i][4] = (_Float16)f1[0]; af[i][5] = (_Float16)f1[1];
            af[i][6] = (_Float16)f1[2]; af[i][7] = (_Float16)f1[3];
        }
        #pragma unroll
        for (int j = 0; j < 4; j++) {
            int brow = wn * 64 + j * 16 + lm;           // local row in the half
            int ch = quad ^ ((brow >> 1) & 3);          // (r>>1)&3 invariant mod 128
            half8 bf = *(const half8*)&Bf[brow * 32 + ch * 8];
            #pragma unroll
            for (int i = 0; i < 4; i++)
                acc[i][j] = __builtin_amdgcn_mfma_f32_16x16x32_f16(af[i], bf, acc[i][j], 0, 0, 0);
        }
        // all waves done reading buf p before next stage overwrites it;
        // deliberately does NOT wait vmcnt — prefetch stays airborne
        asm volatile("s_waitcnt lgkmcnt(0)\n\ts_barrier" ::: "memory");
    }

    #pragma unroll
    for (int i = 0; i < 4; i++) {
        long r0 = row0 + wm * 64 + i * 16 + quad * 4;
        #pragma unroll
        for (int j = 0; j < 4; j++) {
            int c = wn * 64 + j * 16 + lm;              // output channel 0..127
            if (nh) {
                float badd = bias[c];
                #pragma unroll
                for (int rr = 0; rr < 4; rr++) {
                    long r = r0 + rr;
                    if (r < M) Cs[r * HDIM + c] = acc[i][j][rr] + badd;
                }
            } else {
                #pragma unroll
                for (int rr = 0; rr < 4; rr++) {
                    long r = r0 + rr;
                    if (r < M) Cn[r * HDIM + c] = (_Float16)acc[i][j][rr];
                }
            }
        }
    }
}

// -------------------- K=128 N-split GEMM: fp16 A; counted-vmcnt pipeline
__global__ __launch_bounds__(256) void gemm16_ns(
    const _Float16* __restrict__ A, int M,
    const _Float16* __restrict__ Wtp, const float* __restrict__ bias,
    _Float16* __restrict__ Cn, float* __restrict__ Cs) {
    __shared__ _Float16 sbuf[2][8192];   // A 4096 halves + B 4096 halves

    int tid = threadIdx.x;
    int wave = tid >> 6, lane = tid & 63;
    int lm = lane & 15, quad = lane >> 4;
    int wm = wave >> 1, wn = wave & 1;
    int bx = blockIdx.x;
    long row0 = (long)(bx >> 1) * 128;
    int nh = bx & 1;

    floatx4 acc[4][4] = {};

    auto stage = [&](int kb, _Float16* buf) {
        #pragma unroll
        for (int pass = 0; pass < 2; pass++) {
            int q = pass * 256 + tid;
            int r = q >> 2, cc = q & 3;
            int ccg = cc ^ ((r >> 1) & 3);
            long grow = row0 + r;
            if (grow >= M) grow = 0;        // clamp: uniform load count per wave
            cp16(A + grow * (long)HDIM + kb * 32 + ccg * 8,
                 buf + pass * 2048 + wave * 512);
        }
        const _Float16* wsrc = Wtp + (size_t)kb * 8192 + nh * 4096;
        #pragma unroll
        for (int pass = 0; pass < 2; pass++) {
            cp16(wsrc + (size_t)(pass * 256 + tid) * 8,
                 buf + 4096 + pass * 2048 + wave * 512);
        }
    };

    stage(0, sbuf[0]);   // 4 loads in flight

    for (int kb = 0; kb < 4; kb++) {
        int p = kb & 1;
        if (kb + 1 < 4) {
            stage(kb + 1, sbuf[p ^ 1]);
            asm volatile("s_waitcnt vmcnt(4)\n\ts_barrier" ::: "memory");
        } else {
            asm volatile("s_waitcnt vmcnt(0)\n\ts_barrier" ::: "memory");
        }

        const _Float16* bp = sbuf[p];
        half8 af[4];
        #pragma unroll
        for (int i = 0; i < 4; i++) {
            int row = wm * 64 + i * 16 + lm;
            int ch = quad ^ ((row >> 1) & 3);
            af[i] = *(const half8*)&bp[row * 32 + ch * 8];
        }
        #pragma unroll
        for (int j = 0; j < 4; j++) {
            int brow = wn * 64 + j * 16 + lm;
            int ch = quad ^ ((brow >> 1) & 3);
            half8 bf = *(const half8*)&bp[4096 + brow * 32 + ch * 8];
            #pragma unroll
            for (int i = 0; i < 4; i++)
                acc[i][j] = __builtin_amdgcn_mfma_f32_16x16x32_f16(af[i], bf, acc[i][j], 0, 0, 0);
        }
        asm volatile("s_waitcnt lgkmcnt(0)\n\ts_barrier" ::: "memory");
    }

    #pragma unroll
    for (int i = 0; i < 4; i++) {
        long r0 = row0 + wm * 64 + i * 16 + quad * 4;
        #pragma unroll
        for (int j = 0; j < 4; j++) {
            int c = wn * 64 + j * 16 + lm;
            if (nh) {
                float badd = bias[c];
                #pragma unroll
                for (int rr = 0; rr < 4; rr++) {
                    long r = r0 + rr;
                    if (r < M) Cs[r * HDIM + c] = acc[i][j][rr] + badd;
                }
            } else {
                #pragma unroll
                for (int rr = 0; rr < 4; rr++) {
                    long r = r0 + rr;
                    if (r < M) Cn[r * HDIM + c] = (_Float16)acc[i][j][rr];
                }
            }
        }
    }
}

// --------------- aggregation + fused BN stats (stats[NSHARD][256], sharded)
// Each wave finalizes one node's pre row in-register; block combines 4 nodes'
// values (and squares) in LDS, then 2 sharded atomicAdds per channel.
__global__ __launch_bounds__(256) void aggregate_w(
    const _Float16* __restrict__ hn, const int* __restrict__ row_ptr,
    const int* __restrict__ esrc, float* __restrict__ pre,
    float* __restrict__ stats) {
    __shared__ float s1[4][HDIM], s2[4][HDIM];
    int tid = threadIdx.x;
    int wave = tid >> 6, lane = tid & 63;
    int n = blockIdx.x * 4 + wave;
    bool valid = (n < N_NODES);
    int eg = lane >> 4;            // edge slot 0..3
    int c8 = (lane & 15) * 8;      // channel group

    float pv[8] = {};              // final pre values (eg==0 lanes)
    if (valid) {
        int start = row_ptr[n], end = row_ptr[n + 1];
        float acc[8] = {};
        for (int base = start; base < end; base += 16) {
            #pragma unroll
            for (int u = 0; u < 4; u++) {
                int e = base + u * 4 + eg;
                if (e < end) {
                    int s = esrc[e];
                    half8 v = *(const half8*)&hn[(size_t)s * HDIM + c8];
                    #pragma unroll
                    for (int i = 0; i < 8; i++) acc[i] += (float)v[i];
                }
            }
        }
        #pragma unroll
        for (int i = 0; i < 8; i++) {
            acc[i] += __shfl_xor(acc[i], 16, 64);
            acc[i] += __shfl_xor(acc[i], 32, 64);
        }
        if (eg == 0) {
            float rd = 1.0f / (float)max(end - start, 1);
            size_t off = (size_t)n * HDIM + c8;
            float4 p0 = *(float4*)&pre[off];
            float4 p1 = *(float4*)&pre[off + 4];
            p0.x += acc[0] * rd; p0.y += acc[1] * rd;
            p0.z += acc[2] * rd; p0.w += acc[3] * rd;
            p1.x += acc[4] * rd; p1.y += acc[5] * rd;
            p1.z += acc[6] * rd; p1.w += acc[7] * rd;
            *(float4*)&pre[off]     = p0;
            *(float4*)&pre[off + 4] = p1;
            pv[0] = p0.x; pv[1] = p0.y; pv[2] = p0.z; pv[3] = p0.w;
            pv[4] = p1.x; pv[5] = p1.y; pv[6] = p1.z; pv[7] = p1.w;
        }
    }
    if (eg == 0) {
        #pragma unroll
        for (int i = 0; i < 8; i++) {
            float v = valid ? pv[i] : 0.0f;
            s1[wave][c8 + i] = v;
            s2[wave][c8 + i] = v * v;
        }
    }
    __syncthreads();
    if (tid < HDIM) {
        float a = s1[0][tid] + s1[1][tid] + s1[2][tid] + s1[3][tid];
        float b = s2[0][tid] + s2[1][tid] + s2[2][tid] + s2[3][tid];
        float* sh = stats + (size_t)(blockIdx.x & (NSHARD - 1)) * 256;
        atomicAdd(&sh[tid], a);
        atomicAdd(&sh[128 + tid], b);
    }
}

// h16 = fp16(relu(P*scale+shift [+ res16])); stats summed from NSHARD shards
__global__ void bn_apply16(const float* __restrict__ P, const _Float16* __restrict__ res16,
                           _Float16* __restrict__ out16,
                           const float* __restrict__ stats,
                           const float* __restrict__ gamma, const float* __restrict__ beta,
                           int M, int total4, int Cdiv4) {
    __shared__ float ssc[HDIM], ssh[HDIM];
    int tid = threadIdx.x;
    int C = Cdiv4 * 4;
    if (tid < C) {
        float s = 0.0f, s2 = 0.0f;
        #pragma unroll 8
        for (int k = 0; k < NSHARD; k++) {
            s  += stats[k * 256 + tid];
            s2 += stats[k * 256 + 128 + tid];
        }
        float mean = s / (float)M;
        float var = s2 / (float)M - mean * mean;
        float sc = rsqrtf(var + 1e-5f) * gamma[tid];
        ssc[tid] = sc;
        ssh[tid] = beta[tid] - mean * sc;
    }
    __syncthreads();
    for (int f = blockIdx.x * blockDim.x + tid; f < total4;
         f += gridDim.x * blockDim.x) {
        int c4 = (f % Cdiv4) * 4;
        float4 v = ((const float4*)P)[f];
        v.x = v.x * ssc[c4 + 0] + ssh[c4 + 0];
        v.y = v.y * ssc[c4 + 1] + ssh[c4 + 1];
        v.z = v.z * ssc[c4 + 2] + ssh[c4 + 2];
        v.w = v.w * ssc[c4 + 3] + ssh[c4 + 3];
        if (res16) {
            half4 rv = *(const half4*)&res16[(size_t)f * 4];
            v.x += (float)rv[0]; v.y += (float)rv[1];
            v.z += (float)rv[2]; v.w += (float)rv[3];
        }
        half4 h;
        h[0] = (_Float16)fmaxf(v.x, 0.0f); h[1] = (_Float16)fmaxf(v.y, 0.0f);
        h[2] = (_Float16)fmaxf(v.z, 0.0f); h[3] = (_Float16)fmaxf(v.w, 0.0f);
        *(half4*)&out16[(size_t)f * 4] = h;
    }
}

// ------------------------- MLP head with fused Z-stats (sharded, C=64)
__global__ __launch_bounds__(256) void mlp_gemm(const _Float16* __restrict__ H,
                                                const float* __restrict__ W1,
                                                const float* __restrict__ b1,
                                                float* __restrict__ Z,
                                                float* __restrict__ stats, int M) {
    __shared__ float hs[64 * 132];
    __shared__ float ws[128 * 64];
    __shared__ float zs1[16][64], zs2[16][64];
    int tid = threadIdx.x;
    int tx = tid & 15;
    int ty = tid >> 4;
    int row0 = blockIdx.x * 64;

    #pragma unroll
    for (int t = 0; t < 8; t++) {
        int f = tid + t * 256;
        int r = f >> 4, c4 = (f & 15) * 4;
        *(float4*)&ws[r * 64 + c4] = *(const float4*)&W1[r * 64 + c4];
    }
    #pragma unroll
    for (int t = 0; t < 4; t++) {
        int f = tid + t * 256;
        int r = f >> 4, c8 = (f & 15) * 8;
        int gr = row0 + r;
        if (gr < M) {
            half8 hv = *(const half8*)&H[(size_t)gr * HDIM + c8];
            #pragma unroll
            for (int i = 0; i < 8; i++) hs[r * 132 + c8 + i] = (float)hv[i];
        } else {
            #pragma unroll
            for (int i = 0; i < 8; i++) hs[r * 132 + c8 + i] = 0.0f;
        }
    }
    __syncthreads();

    float acc[4][4] = {};
    for (int k = 0; k < 128; k++) {
        float a[4];
        #pragma unroll
        for (int i = 0; i < 4; i++) a[i] = hs[(ty * 4 + i) * 132 + k];
        float4 b4 = *(const float4*)&ws[k * 64 + tx * 4];
        #pragma unroll
        for (int i = 0; i < 4; i++) {
            acc[i][0] += a[i] * b4.x; acc[i][1] += a[i] * b4.y;
            acc[i][2] += a[i] * b4.z; acc[i][3] += a[i] * b4.w;
        }
    }
    float4 bb = *(const float4*)&b1[tx * 4];
    float cs[4] = {}, cq[4] = {};
    #pragma unroll
    for (int i = 0; i < 4; i++) {
        int r = row0 + ty * 4 + i;
        if (r < M) {
            float v0 = acc[i][0] + bb.x;
            float v1 = acc[i][1] + bb.y;
            float v2 = acc[i][2] + bb.z;
            float v3 = acc[i][3] + bb.w;
            float4 v = {v0, v1, v2, v3};
            *(float4*)&Z[(size_t)r * 64 + tx * 4] = v;
            cs[0] += v0; cq[0] += v0 * v0;
            cs[1] += v1; cq[1] += v1 * v1;
            cs[2] += v2; cq[2] += v2 * v2;
            cs[3] += v3; cq[3] += v3 * v3;
        }
    }
    #pragma unroll
    for (int j = 0; j < 4; j++) {
        zs1[ty][tx * 4 + j] = cs[j];
        zs2[ty][tx * 4 + j] = cq[j];
    }
    __syncthreads();
    if (tid < 64) {
        float a = 0.0f, b = 0.0f;
        #pragma unroll
        for (int k = 0; k < 16; k++) { a += zs1[k][tid]; b += zs2[k][tid]; }
        float* sh = stats + (size_t)(blockIdx.x & (NSHARD - 1)) * 256;
        atomicAdd(&sh[tid], a);
        atomicAdd(&sh[128 + tid], b);
    }
}

// out[n] = relu(bn(Z[n,:])) . W2 + b2  — BN finalize+apply fused into the dot
__global__ void final_out(const float* __restrict__ Z,
                          const float* __restrict__ stats,
                          const float* __restrict__ gamma, const float* __restrict__ beta,
                          const float* __restrict__ W2, const float* __restrict__ b2,
                          float* __restrict__ out, int M) {
    __shared__ float ssc[64], ssh[64], sw[64];
    int tid = threadIdx.x;
    if (tid < 64) {
        float s = 0.0f, s2 = 0.0f;
        #pragma unroll 8
        for (int k = 0; k < NSHARD; k++) {
            s  += stats[k * 256 + tid];
            s2 += stats[k * 256 + 128 + tid];
        }
        float mean = s / (float)M;
        float var = s2 / (float)M - mean * mean;
        float sc = rsqrtf(var + 1e-5f) * gamma[tid];
        ssc[tid] = sc;
        ssh[tid] = beta[tid] - mean * sc;
        sw[tid] = W2[tid];
    }
    __syncthreads();
    int n = blockIdx.x * 4 + (tid >> 6);
    int lane = tid & 63;
    if (n >= N_NODES) return;
    float z = Z[(size_t)n * 64 + lane] * ssc[lane] + ssh[lane];
    z = fmaxf(z, 0.0f);
    float v = z * sw[lane];
    #pragma unroll
    for (int off = 32; off >= 1; off >>= 1) v += __shfl_down(v, off, 64);
    if (lane == 0) out[n] = v + b2[0];
}

// ------------------------------------------------------------------ driver
extern "C" void kernel_launch(void* const* d_in, const int* in_sizes, int n_in,
                              void* d_out, int out_size, void* d_ws, size_t ws_size,
                              hipStream_t stream) {
    const float* X       = (const float*)d_in[0];
    const int*   graph   = (const int*)d_in[1];
    const float* Wself0  = (const float*)d_in[2];
    const float* Wneigh0 = (const float*)d_in[3];
    const float* b0      = (const float*)d_in[4];
    const float* Wself   = (const float*)d_in[5];
    const float* Wneigh  = (const float*)d_in[6];
    const float* bvec    = (const float*)d_in[7];
    const float* bn_g    = (const float*)d_in[8];
    const float* bn_b    = (const float*)d_in[9];
    const float* W1      = (const float*)d_in[10];
    const float* b1      = (const float*)d_in[11];
    const float* bng1    = (const float*)d_in[12];
    const float* bnb1    = (const float*)d_in[13];
    const float* W2      = (const float*)d_in[14];
    const float* b2      = (const float*)d_in[15];
    float* out = (float*)d_out;

    size_t off = 0;
    auto alloc = [&](size_t bytes) {
        void* p = (char*)d_ws + off;
        off += (bytes + 255) & ~(size_t)255;
        return p;
    };
    int* cnt     = (int*)alloc(N_NODES * 4);
    int* cursor  = (int*)alloc(N_NODES * 4);
    int* row_ptr = (int*)alloc((N_NODES + 1) * 4);
    int* incl    = (int*)alloc(N_NODES * 4);
    int* blk     = (int*)alloc(NB_SCAN * 4);
    int* blkoff  = (int*)alloc(NB_SCAN * 4);
    int* esrc    = (int*)alloc((size_t)N_EDGES * 4);
    float*    pre   = (float*)alloc((size_t)N_NODES * HDIM * 4);    // 51.2 MB
    _Float16* h16A  = (_Float16*)alloc((size_t)N_NODES * HDIM * 2); // 25.6 MB
    _Float16* h16B  = (_Float16*)alloc((size_t)N_NODES * HDIM * 2);
    _Float16* hn16  = (_Float16*)alloc((size_t)N_NODES * HDIM * 2);
    float*    Z     = (float*)alloc((size_t)N_NODES * 64 * 4);
    _Float16* Wtp0  = (_Float16*)alloc((size_t)NKB0 * 8192 * 2);
    _Float16* Wtpl  = (_Float16*)alloc((size_t)3 * 4 * 8192 * 2);
    float*    zbuf  = (float*)alloc(256);
    float*    stats = (float*)alloc((size_t)NSHARD * 256 * 4);      // 64 KB

    const int EB = (N_EDGES + 255) / 256;
    const int GB = ((N_NODES + 127) / 128) * 2;   // 1564 (M-tiles x 2 N-halves)
    const int AGB = (N_NODES + 3) / 4;            // 25000
    const size_t STB = (size_t)NSHARD * 256 * 4;

    // CSR build
    hipMemsetAsync(cnt, 0, N_NODES * 4, stream);
    hipMemsetAsync(cursor, 0, N_NODES * 4, stream);
    hipMemsetAsync(zbuf, 0, 256, stream);
    count_edges<<<EB, 256, 0, stream>>>(graph, cnt);
    scan1<<<NB_SCAN, SCAN_B, 0, stream>>>(cnt, incl, blk);
    scan2<<<1, 512, 0, stream>>>(blk, blkoff);
    scan3<<<NB_SCAN, SCAN_B, 0, stream>>>(incl, blkoff, row_ptr);
    fill_edges<<<EB, 256, 0, stream>>>(graph, row_ptr, cursor, esrc);

    // weight packs
    build_wtp0<<<(NKB0 * 1024 + 255) / 256, 256, 0, stream>>>(Wneigh0, Wself0, Wtp0);
    build_wtpl<<<(3 * 4096 + 255) / 256, 256, 0, stream>>>(Wneigh, Wself, Wtpl);

    _Float16* hc = h16A;
    _Float16* hx = h16B;

    // ---- layer 0 (K = 700, fp32 A direct, N-split; stats fused in aggregate)
    gemm0_ns<<<GB, 256, 0, stream>>>(X, N_NODES, F_IN, Wtp0, b0, zbuf, hn16, pre);
    hipMemsetAsync(stats, 0, STB, stream);
    aggregate_w<<<AGB, 256, 0, stream>>>(hn16, row_ptr, esrc, pre, stats);
    bn_apply16<<<1024, 256, 0, stream>>>(pre, nullptr, hc, stats,
                                         bn_g, bn_b, N_NODES,
                                         N_NODES * HDIM / 4, HDIM / 4);

    // ---- layers 1..3 (K = 128, residual in fp16, N-split)
    for (int l = 0; l < 3; l++) {
        gemm16_ns<<<GB, 256, 0, stream>>>(hc, N_NODES, Wtpl + (size_t)l * 32768,
                                          bvec + l * HDIM, hn16, pre);
        hipMemsetAsync(stats, 0, STB, stream);
        aggregate_w<<<AGB, 256, 0, stream>>>(hn16, row_ptr, esrc, pre, stats);
        bn_apply16<<<1024, 256, 0, stream>>>(pre, hc, hx, stats,
                                             bn_g + (l + 1) * HDIM,
                                             bn_b + (l + 1) * HDIM, N_NODES,
                                             N_NODES * HDIM / 4, HDIM / 4);
        _Float16* t = hc; hc = hx; hx = t;
    }

    // ---- MLP head (Z-stats fused into mlp_gemm; BN finalize in final_out)
    hipMemsetAsync(stats, 0, STB, stream);
    mlp_gemm<<<(N_NODES + 63) / 64, 256, 0, stream>>>(hc, W1, b1, Z, stats, N_NODES);
    final_out<<<AGB, 256, 0, stream>>>(Z, stats, bng1, bnb1, W2, b2,
                                       out, N_NODES);
}

// Round 6
// 1198.768 us; speedup vs baseline: 1.1151x; 1.0081x over previous
//
#include <hip/hip_runtime.h>
#include <hip/hip_bf16.h>

#define N_NODES 100000
#define N_EDGES 1600000
#define F_IN    700
#define NKB0    22          // ceil(700/32)
#define HDIM    128
#define SCAN_B  256
#define NB_SCAN ((N_NODES + SCAN_B - 1) / SCAN_B)   // 391
#define NSHARD  64          // stats shards: stats[NSHARD][256] (sum | sumsq@+128)

typedef _Float16 half8 __attribute__((ext_vector_type(8)));
typedef _Float16 half4 __attribute__((ext_vector_type(4)));
typedef float floatx4 __attribute__((ext_vector_type(4)));

// async global->LDS, 16B per lane; dst slot = wave-uniform base + lane*16
__device__ __forceinline__ void cp16(const void* g, void* l) {
    __builtin_amdgcn_global_load_lds(
        (const __attribute__((address_space(1))) void*)g,
        (__attribute__((address_space(3))) void*)l, 16, 0, 0);
}

// ---------------------------------------------------------------- CSR build
__global__ void count_edges(const int* __restrict__ graph, int* __restrict__ cnt) {
    int e = blockIdx.x * blockDim.x + threadIdx.x;
    if (e < N_EDGES) atomicAdd(&cnt[graph[2 * e + 1]], 1);
}

__global__ void scan1(const int* __restrict__ cnt, int* __restrict__ incl,
                      int* __restrict__ blk) {
    __shared__ int s[SCAN_B];
    int tid = threadIdx.x;
    int i = blockIdx.x * SCAN_B + tid;
    s[tid] = (i < N_NODES) ? cnt[i] : 0;
    __syncthreads();
    for (int off = 1; off < SCAN_B; off <<= 1) {
        int t = (tid >= off) ? s[tid - off] : 0;
        __syncthreads();
        s[tid] += t;
        __syncthreads();
    }
    if (i < N_NODES) incl[i] = s[tid];
    if (tid == SCAN_B - 1) blk[blockIdx.x] = s[tid];
}

__global__ void scan2(const int* __restrict__ blk, int* __restrict__ blkoff) {
    __shared__ int s[512];
    int tid = threadIdx.x;
    s[tid] = (tid < NB_SCAN) ? blk[tid] : 0;
    __syncthreads();
    for (int off = 1; off < 512; off <<= 1) {
        int t = (tid >= off) ? s[tid - off] : 0;
        __syncthreads();
        s[tid] += t;
        __syncthreads();
    }
    if (tid < NB_SCAN) blkoff[tid] = (tid == 0) ? 0 : s[tid - 1];
}

__global__ void scan3(const int* __restrict__ incl, const int* __restrict__ blkoff,
                      int* __restrict__ row_ptr) {
    int i = blockIdx.x * SCAN_B + threadIdx.x;
    if (i < N_NODES) {
        row_ptr[i + 1] = incl[i] + blkoff[i >> 8];
        if (i == 0) row_ptr[0] = 0;
    }
}

__global__ void fill_edges(const int* __restrict__ graph, const int* __restrict__ row_ptr,
                           int* __restrict__ cursor, int* __restrict__ esrc) {
    int e = blockIdx.x * blockDim.x + threadIdx.x;
    if (e < N_EDGES) {
        int src = graph[2 * e];
        int dst = graph[2 * e + 1];
        esrc[row_ptr[dst] + atomicAdd(&cursor[dst], 1)] = src;
    }
}

// ------------------- weight packs: tile-major, XOR-swizzled LDS image (fp16)
__global__ void build_wtp0(const float* __restrict__ Wn, const float* __restrict__ Ws,
                           _Float16* __restrict__ out) {
    int q = blockIdx.x * blockDim.x + threadIdx.x;
    if (q >= NKB0 * 256 * 4) return;
    int kb = q >> 10;
    int r  = (q >> 2) & 255;
    int cc = q & 3;
    int k0 = kb * 32 + (cc ^ ((r >> 1) & 3)) * 8;
    half8 v;
    #pragma unroll
    for (int e = 0; e < 8; e++) {
        int k = k0 + e;
        float f = 0.0f;
        if (k < F_IN) f = (r < 128) ? Wn[k * 128 + r] : Ws[k * 128 + (r - 128)];
        v[e] = (_Float16)f;
    }
    *(half8*)&out[(size_t)q * 8] = v;
}

__global__ void build_wtpl(const float* __restrict__ Wn, const float* __restrict__ Ws,
                           _Float16* __restrict__ out) {
    int q = blockIdx.x * blockDim.x + threadIdx.x;
    if (q >= 3 * 4 * 256 * 4) return;
    int l = q >> 12;
    int rem = q & 4095;
    int kb = rem >> 10;
    int r  = (rem >> 2) & 255;
    int cc = rem & 3;
    int k0 = kb * 32 + (cc ^ ((r >> 1) & 3)) * 8;
    half8 v;
    #pragma unroll
    for (int e = 0; e < 8; e++) {
        int k = k0 + e;
        float f = (r < 128) ? Wn[l * 16384 + k * 128 + r]
                            : Ws[l * 16384 + k * 128 + (r - 128)];
        v[e] = (_Float16)f;
    }
    *(half8*)&out[(size_t)q * 8] = v;
}

// ----------------- layer-0 N-split GEMM: fp32 A staged raw, cvt at frag read
// T4 counted-vmcnt pipeline; self-half output now fp16 (traffic cut).
__global__ __launch_bounds__(256) void gemm0_ns(
    const float* __restrict__ A, int M, int K,
    const _Float16* __restrict__ Wtp, const float* __restrict__ bias,
    const float* __restrict__ zbuf,
    _Float16* __restrict__ Cn, _Float16* __restrict__ Cs) {
    __shared__ char sbuf[2][24576];

    int tid = threadIdx.x;
    int wave = tid >> 6, lane = tid & 63;
    int lm = lane & 15, quad = lane >> 4;
    int wm = wave >> 1, wn = wave & 1;      // 2x2 waves: 64 rows x 64 cols each
    int bx = blockIdx.x;
    long row0 = (long)(bx >> 1) * 128;
    int nh = bx & 1;

    floatx4 acc[4][4] = {};

    auto stage = [&](int kb, char* buf) {
        // A: 1024 16B chunks (4 floats), XOR-swizzled slot cc holds chunk cc^(r&7)
        #pragma unroll
        for (int pass = 0; pass < 4; pass++) {
            int q = pass * 256 + tid;
            int r = q >> 3, cc = q & 7;
            int ccg = cc ^ (r & 7);
            long grow = row0 + r;
            if (grow >= M) grow = 0;        // clamp: uniform load count per wave
            int gk = kb * 32 + ccg * 4;
            const float* src = (gk + 4 <= K) ? (A + grow * (long)K + gk) : zbuf;
            cp16(src, buf + pass * 4096 + wave * 1024);
        }
        // B half: 512 chunks, linear (pre-swizzled at pack time)
        const _Float16* wsrc = Wtp + (size_t)kb * 8192 + nh * 4096;
        #pragma unroll
        for (int pass = 0; pass < 2; pass++) {
            cp16(wsrc + (size_t)(pass * 256 + tid) * 8,
                 buf + 16384 + pass * 4096 + wave * 1024);
        }
    };

    stage(0, sbuf[0]);   // 6 loads in flight; waited inside the loop

    for (int kb = 0; kb < NKB0; kb++) {
        int p = kb & 1;
        if (kb + 1 < NKB0) {
            stage(kb + 1, sbuf[p ^ 1]);
            // wait for tile kb's 6 loads; tile kb+1's 6 stay in flight
            asm volatile("s_waitcnt vmcnt(6)\n\ts_barrier" ::: "memory");
        } else {
            asm volatile("s_waitcnt vmcnt(0)\n\ts_barrier" ::: "memory");
        }

        const float* Af = (const float*)sbuf[p];
        const _Float16* Bf = (const _Float16*)(sbuf[p] + 16384);
        half8 af[4];
        #pragma unroll
        for (int i = 0; i < 4; i++) {
            int row = wm * 64 + i * 16 + lm;
            int c0 = (quad * 2) ^ (row & 7);
            int c1 = (quad * 2 + 1) ^ (row & 7);
            floatx4 f0 = *(const floatx4*)&Af[row * 32 + c0 * 4];
            floatx4 f1 = *(const floatx4*)&Af[row * 32 + c1 * 4];
            af[i][0] = (_Float16)f0[0]; af[i][1] = (_Float16)f0[1];
            af[i][2] = (_Float16)f0[2]; af[i][3] = (_Float16)f0[3];
            af[i][4] = (_Float16)f1[0]; af[i][5] = (_Float16)f1[1];
            af[i][6] = (_Float16)f1[2]; af[i][7] = (_Float16)f1[3];
        }
        #pragma unroll
        for (int j = 0; j < 4; j++) {
            int brow = wn * 64 + j * 16 + lm;           // local row in the half
            int ch = quad ^ ((brow >> 1) & 3);          // (r>>1)&3 invariant mod 128
            half8 bf = *(const half8*)&Bf[brow * 32 + ch * 8];
            #pragma unroll
            for (int i = 0; i < 4; i++)
                acc[i][j] = __builtin_amdgcn_mfma_f32_16x16x32_f16(af[i], bf, acc[i][j], 0, 0, 0);
        }
        // all waves done reading buf p before next stage overwrites it;
        // deliberately does NOT wait vmcnt — prefetch stays airborne
        asm volatile("s_waitcnt lgkmcnt(0)\n\ts_barrier" ::: "memory");
    }

    #pragma unroll
    for (int i = 0; i < 4; i++) {
        long r0 = row0 + wm * 64 + i * 16 + quad * 4;
        #pragma unroll
        for (int j = 0; j < 4; j++) {
            int c = wn * 64 + j * 16 + lm;              // output channel 0..127
            if (nh) {
                float badd = bias[c];
                #pragma unroll
                for (int rr = 0; rr < 4; rr++) {
                    long r = r0 + rr;
                    if (r < M) Cs[r * HDIM + c] = (_Float16)(acc[i][j][rr] + badd);
                }
            } else {
                #pragma unroll
                for (int rr = 0; rr < 4; rr++) {
                    long r = r0 + rr;
                    if (r < M) Cn[r * HDIM + c] = (_Float16)acc[i][j][rr];
                }
            }
        }
    }
}

// -------------------- K=128 N-split GEMM: fp16 A; counted-vmcnt pipeline
__global__ __launch_bounds__(256) void gemm16_ns(
    const _Float16* __restrict__ A, int M,
    const _Float16* __restrict__ Wtp, const float* __restrict__ bias,
    _Float16* __restrict__ Cn, _Float16* __restrict__ Cs) {
    __shared__ _Float16 sbuf[2][8192];   // A 4096 halves + B 4096 halves

    int tid = threadIdx.x;
    int wave = tid >> 6, lane = tid & 63;
    int lm = lane & 15, quad = lane >> 4;
    int wm = wave >> 1, wn = wave & 1;
    int bx = blockIdx.x;
    long row0 = (long)(bx >> 1) * 128;
    int nh = bx & 1;

    floatx4 acc[4][4] = {};

    auto stage = [&](int kb, _Float16* buf) {
        #pragma unroll
        for (int pass = 0; pass < 2; pass++) {
            int q = pass * 256 + tid;
            int r = q >> 2, cc = q & 3;
            int ccg = cc ^ ((r >> 1) & 3);
            long grow = row0 + r;
            if (grow >= M) grow = 0;        // clamp: uniform load count per wave
            cp16(A + grow * (long)HDIM + kb * 32 + ccg * 8,
                 buf + pass * 2048 + wave * 512);
        }
        const _Float16* wsrc = Wtp + (size_t)kb * 8192 + nh * 4096;
        #pragma unroll
        for (int pass = 0; pass < 2; pass++) {
            cp16(wsrc + (size_t)(pass * 256 + tid) * 8,
                 buf + 4096 + pass * 2048 + wave * 512);
        }
    };

    stage(0, sbuf[0]);   // 4 loads in flight

    for (int kb = 0; kb < 4; kb++) {
        int p = kb & 1;
        if (kb + 1 < 4) {
            stage(kb + 1, sbuf[p ^ 1]);
            asm volatile("s_waitcnt vmcnt(4)\n\ts_barrier" ::: "memory");
        } else {
            asm volatile("s_waitcnt vmcnt(0)\n\ts_barrier" ::: "memory");
        }

        const _Float16* bp = sbuf[p];
        half8 af[4];
        #pragma unroll
        for (int i = 0; i < 4; i++) {
            int row = wm * 64 + i * 16 + lm;
            int ch = quad ^ ((row >> 1) & 3);
            af[i] = *(const half8*)&bp[row * 32 + ch * 8];
        }
        #pragma unroll
        for (int j = 0; j < 4; j++) {
            int brow = wn * 64 + j * 16 + lm;
            int ch = quad ^ ((brow >> 1) & 3);
            half8 bf = *(const half8*)&bp[4096 + brow * 32 + ch * 8];
            #pragma unroll
            for (int i = 0; i < 4; i++)
                acc[i][j] = __builtin_amdgcn_mfma_f32_16x16x32_f16(af[i], bf, acc[i][j], 0, 0, 0);
        }
        asm volatile("s_waitcnt lgkmcnt(0)\n\ts_barrier" ::: "memory");
    }

    #pragma unroll
    for (int i = 0; i < 4; i++) {
        long r0 = row0 + wm * 64 + i * 16 + quad * 4;
        #pragma unroll
        for (int j = 0; j < 4; j++) {
            int c = wn * 64 + j * 16 + lm;
            if (nh) {
                float badd = bias[c];
                #pragma unroll
                for (int rr = 0; rr < 4; rr++) {
                    long r = r0 + rr;
                    if (r < M) Cs[r * HDIM + c] = (_Float16)(acc[i][j][rr] + badd);
                }
            } else {
                #pragma unroll
                for (int rr = 0; rr < 4; rr++) {
                    long r = r0 + rr;
                    if (r < M) Cn[r * HDIM + c] = (_Float16)acc[i][j][rr];
                }
            }
        }
    }
}

// --------------- aggregation + fused BN stats (stats[NSHARD][256], sharded)
// Reads self-part cs16 (fp16), writes pre16 (fp16, write-only — no RMW);
// stats from fp32 pre-round values. Block combines 4 nodes in LDS, then 2
// sharded atomicAdds per channel.
__global__ __launch_bounds__(256) void aggregate_w(
    const _Float16* __restrict__ hn, const int* __restrict__ row_ptr,
    const int* __restrict__ esrc, const _Float16* __restrict__ cs16,
    _Float16* __restrict__ pre16, float* __restrict__ stats) {
    __shared__ float s1[4][HDIM], s2[4][HDIM];
    int tid = threadIdx.x;
    int wave = tid >> 6, lane = tid & 63;
    int n = blockIdx.x * 4 + wave;
    bool valid = (n < N_NODES);
    int eg = lane >> 4;            // edge slot 0..3
    int c8 = (lane & 15) * 8;      // channel group

    float pv[8] = {};              // final pre values (eg==0 lanes)
    if (valid) {
        int start = row_ptr[n], end = row_ptr[n + 1];
        float acc[8] = {};
        for (int base = start; base < end; base += 16) {
            #pragma unroll
            for (int u = 0; u < 4; u++) {
                int e = base + u * 4 + eg;
                if (e < end) {
                    int s = esrc[e];
                    half8 v = *(const half8*)&hn[(size_t)s * HDIM + c8];
                    #pragma unroll
                    for (int i = 0; i < 8; i++) acc[i] += (float)v[i];
                }
            }
        }
        #pragma unroll
        for (int i = 0; i < 8; i++) {
            acc[i] += __shfl_xor(acc[i], 16, 64);
            acc[i] += __shfl_xor(acc[i], 32, 64);
        }
        if (eg == 0) {
            float rd = 1.0f / (float)max(end - start, 1);
            half8 sv = *(const half8*)&cs16[(size_t)n * HDIM + c8];
            half8 h;
            #pragma unroll
            for (int i = 0; i < 8; i++) {
                pv[i] = acc[i] * rd + (float)sv[i];
                h[i] = (_Float16)pv[i];
            }
            *(half8*)&pre16[(size_t)n * HDIM + c8] = h;
        }
    }
    if (eg == 0) {
        #pragma unroll
        for (int i = 0; i < 8; i++) {
            float v = valid ? pv[i] : 0.0f;
            s1[wave][c8 + i] = v;
            s2[wave][c8 + i] = v * v;
        }
    }
    __syncthreads();
    if (tid < HDIM) {
        float a = s1[0][tid] + s1[1][tid] + s1[2][tid] + s1[3][tid];
        float b = s2[0][tid] + s2[1][tid] + s2[2][tid] + s2[3][tid];
        float* sh = stats + (size_t)(blockIdx.x & (NSHARD - 1)) * 256;
        atomicAdd(&sh[tid], a);
        atomicAdd(&sh[128 + tid], b);
    }
}

// h16 = fp16(relu(P*scale+shift [+ res16])); P fp16, 8-wide; stats from shards
__global__ void bn_apply16(const _Float16* __restrict__ P, const _Float16* __restrict__ res16,
                           _Float16* __restrict__ out16,
                           const float* __restrict__ stats,
                           const float* __restrict__ gamma, const float* __restrict__ beta,
                           int M, int total8, int Cdiv8) {
    __shared__ float ssc[HDIM], ssh[HDIM];
    int tid = threadIdx.x;
    int C = Cdiv8 * 8;
    if (tid < C) {
        float s = 0.0f, s2 = 0.0f;
        #pragma unroll 8
        for (int k = 0; k < NSHARD; k++) {
            s  += stats[k * 256 + tid];
            s2 += stats[k * 256 + 128 + tid];
        }
        float mean = s / (float)M;
        float var = s2 / (float)M - mean * mean;
        float sc = rsqrtf(var + 1e-5f) * gamma[tid];
        ssc[tid] = sc;
        ssh[tid] = beta[tid] - mean * sc;
    }
    __syncthreads();
    for (int f = blockIdx.x * blockDim.x + tid; f < total8;
         f += gridDim.x * blockDim.x) {
        int c8 = (f % Cdiv8) * 8;
        half8 v = *(const half8*)&P[(size_t)f * 8];
        half8 h;
        if (res16) {
            half8 rv = *(const half8*)&res16[(size_t)f * 8];
            #pragma unroll
            for (int i = 0; i < 8; i++) {
                float x = (float)v[i] * ssc[c8 + i] + ssh[c8 + i] + (float)rv[i];
                h[i] = (_Float16)fmaxf(x, 0.0f);
            }
        } else {
            #pragma unroll
            for (int i = 0; i < 8; i++) {
                float x = (float)v[i] * ssc[c8 + i] + ssh[c8 + i];
                h[i] = (_Float16)fmaxf(x, 0.0f);
            }
        }
        *(half8*)&out16[(size_t)f * 8] = h;
    }
}

// ------------------------- MLP head with fused Z-stats (sharded, C=64)
__global__ __launch_bounds__(256) void mlp_gemm(const _Float16* __restrict__ H,
                                                const float* __restrict__ W1,
                                                const float* __restrict__ b1,
                                                float* __restrict__ Z,
                                                float* __restrict__ stats, int M) {
    __shared__ float hs[64 * 132];
    __shared__ float ws[128 * 64];
    __shared__ float zs1[16][64], zs2[16][64];
    int tid = threadIdx.x;
    int tx = tid & 15;
    int ty = tid >> 4;
    int row0 = blockIdx.x * 64;

    #pragma unroll
    for (int t = 0; t < 8; t++) {
        int f = tid + t * 256;
        int r = f >> 4, c4 = (f & 15) * 4;
        *(float4*)&ws[r * 64 + c4] = *(const float4*)&W1[r * 64 + c4];
    }
    #pragma unroll
    for (int t = 0; t < 4; t++) {
        int f = tid + t * 256;
        int r = f >> 4, c8 = (f & 15) * 8;
        int gr = row0 + r;
        if (gr < M) {
            half8 hv = *(const half8*)&H[(size_t)gr * HDIM + c8];
            #pragma unroll
            for (int i = 0; i < 8; i++) hs[r * 132 + c8 + i] = (float)hv[i];
        } else {
            #pragma unroll
            for (int i = 0; i < 8; i++) hs[r * 132 + c8 + i] = 0.0f;
        }
    }
    __syncthreads();

    float acc[4][4] = {};
    for (int k = 0; k < 128; k++) {
        float a[4];
        #pragma unroll
        for (int i = 0; i < 4; i++) a[i] = hs[(ty * 4 + i) * 132 + k];
        float4 b4 = *(const float4*)&ws[k * 64 + tx * 4];
        #pragma unroll
        for (int i = 0; i < 4; i++) {
            acc[i][0] += a[i] * b4.x; acc[i][1] += a[i] * b4.y;
            acc[i][2] += a[i] * b4.z; acc[i][3] += a[i] * b4.w;
        }
    }
    float4 bb = *(const float4*)&b1[tx * 4];
    float cs[4] = {}, cq[4] = {};
    #pragma unroll
    for (int i = 0; i < 4; i++) {
        int r = row0 + ty * 4 + i;
        if (r < M) {
            float v0 = acc[i][0] + bb.x;
            float v1 = acc[i][1] + bb.y;
            float v2 = acc[i][2] + bb.z;
            float v3 = acc[i][3] + bb.w;
            float4 v = {v0, v1, v2, v3};
            *(float4*)&Z[(size_t)r * 64 + tx * 4] = v;
            cs[0] += v0; cq[0] += v0 * v0;
            cs[1] += v1; cq[1] += v1 * v1;
            cs[2] += v2; cq[2] += v2 * v2;
            cs[3] += v3; cq[3] += v3 * v3;
        }
    }
    #pragma unroll
    for (int j = 0; j < 4; j++) {
        zs1[ty][tx * 4 + j] = cs[j];
        zs2[ty][tx * 4 + j] = cq[j];
    }
    __syncthreads();
    if (tid < 64) {
        float a = 0.0f, b = 0.0f;
        #pragma unroll
        for (int k = 0; k < 16; k++) { a += zs1[k][tid]; b += zs2[k][tid]; }
        float* sh = stats + (size_t)(blockIdx.x & (NSHARD - 1)) * 256;
        atomicAdd(&sh[tid], a);
        atomicAdd(&sh[128 + tid], b);
    }
}

// out[n] = relu(bn(Z[n,:])) . W2 + b2  — BN finalize+apply fused into the dot
__global__ void final_out(const float* __restrict__ Z,
                          const float* __restrict__ stats,
                          const float* __restrict__ gamma, const float* __restrict__ beta,
                          const float* __restrict__ W2, const float* __restrict__ b2,
                          float* __restrict__ out, int M) {
    __shared__ float ssc[64], ssh[64], sw[64];
    int tid = threadIdx.x;
    if (tid < 64) {
        float s = 0.0f, s2 = 0.0f;
        #pragma unroll 8
        for (int k = 0; k < NSHARD; k++) {
            s  += stats[k * 256 + tid];
            s2 += stats[k * 256 + 128 + tid];
        }
        float mean = s / (float)M;
        float var = s2 / (float)M - mean * mean;
        float sc = rsqrtf(var + 1e-5f) * gamma[tid];
        ssc[tid] = sc;
        ssh[tid] = beta[tid] - mean * sc;
        sw[tid] = W2[tid];
    }
    __syncthreads();
    int n = blockIdx.x * 4 + (tid >> 6);
    int lane = tid & 63;
    if (n >= N_NODES) return;
    float z = Z[(size_t)n * 64 + lane] * ssc[lane] + ssh[lane];
    z = fmaxf(z, 0.0f);
    float v = z * sw[lane];
    #pragma unroll
    for (int off = 32; off >= 1; off >>= 1) v += __shfl_down(v, off, 64);
    if (lane == 0) out[n] = v + b2[0];
}

// ------------------------------------------------------------------ driver
extern "C" void kernel_launch(void* const* d_in, const int* in_sizes, int n_in,
                              void* d_out, int out_size, void* d_ws, size_t ws_size,
                              hipStream_t stream) {
    const float* X       = (const float*)d_in[0];
    const int*   graph   = (const int*)d_in[1];
    const float* Wself0  = (const float*)d_in[2];
    const float* Wneigh0 = (const float*)d_in[3];
    const float* b0      = (const float*)d_in[4];
    const float* Wself   = (const float*)d_in[5];
    const float* Wneigh  = (const float*)d_in[6];
    const float* bvec    = (const float*)d_in[7];
    const float* bn_g    = (const float*)d_in[8];
    const float* bn_b    = (const float*)d_in[9];
    const float* W1      = (const float*)d_in[10];
    const float* b1      = (const float*)d_in[11];
    const float* bng1    = (const float*)d_in[12];
    const float* bnb1    = (const float*)d_in[13];
    const float* W2      = (const float*)d_in[14];
    const float* b2      = (const float*)d_in[15];
    float* out = (float*)d_out;

    size_t off = 0;
    auto alloc = [&](size_t bytes) {
        void* p = (char*)d_ws + off;
        off += (bytes + 255) & ~(size_t)255;
        return p;
    };
    int* cnt     = (int*)alloc(N_NODES * 4);
    int* cursor  = (int*)alloc(N_NODES * 4);
    int* row_ptr = (int*)alloc((N_NODES + 1) * 4);
    int* incl    = (int*)alloc(N_NODES * 4);
    int* blk     = (int*)alloc(NB_SCAN * 4);
    int* blkoff  = (int*)alloc(NB_SCAN * 4);
    int* esrc    = (int*)alloc((size_t)N_EDGES * 4);
    _Float16* pre16 = (_Float16*)alloc((size_t)N_NODES * HDIM * 2); // 25.6 MB
    _Float16* cs16  = (_Float16*)alloc((size_t)N_NODES * HDIM * 2); // 25.6 MB
    _Float16* h16A  = (_Float16*)alloc((size_t)N_NODES * HDIM * 2); // 25.6 MB
    _Float16* h16B  = (_Float16*)alloc((size_t)N_NODES * HDIM * 2);
    _Float16* hn16  = (_Float16*)alloc((size_t)N_NODES * HDIM * 2);
    float*    Z     = (float*)alloc((size_t)N_NODES * 64 * 4);
    _Float16* Wtp0  = (_Float16*)alloc((size_t)NKB0 * 8192 * 2);
    _Float16* Wtpl  = (_Float16*)alloc((size_t)3 * 4 * 8192 * 2);
    float*    zbuf  = (float*)alloc(256);
    float*    stats = (float*)alloc((size_t)NSHARD * 256 * 4);      // 64 KB

    const int EB = (N_EDGES + 255) / 256;
    const int GB = ((N_NODES + 127) / 128) * 2;   // 1564 (M-tiles x 2 N-halves)
    const int AGB = (N_NODES + 3) / 4;            // 25000
    const size_t STB = (size_t)NSHARD * 256 * 4;
    const int TOT8 = N_NODES * HDIM / 8;

    // CSR build
    hipMemsetAsync(cnt, 0, N_NODES * 4, stream);
    hipMemsetAsync(cursor, 0, N_NODES * 4, stream);
    hipMemsetAsync(zbuf, 0, 256, stream);
    count_edges<<<EB, 256, 0, stream>>>(graph, cnt);
    scan1<<<NB_SCAN, SCAN_B, 0, stream>>>(cnt, incl, blk);
    scan2<<<1, 512, 0, stream>>>(blk, blkoff);
    scan3<<<NB_SCAN, SCAN_B, 0, stream>>>(incl, blkoff, row_ptr);
    fill_edges<<<EB, 256, 0, stream>>>(graph, row_ptr, cursor, esrc);

    // weight packs
    build_wtp0<<<(NKB0 * 1024 + 255) / 256, 256, 0, stream>>>(Wneigh0, Wself0, Wtp0);
    build_wtpl<<<(3 * 4096 + 255) / 256, 256, 0, stream>>>(Wneigh, Wself, Wtpl);

    _Float16* hc = h16A;
    _Float16* hx = h16B;

    // ---- layer 0 (K = 700, fp32 A direct, N-split; stats fused in aggregate)
    gemm0_ns<<<GB, 256, 0, stream>>>(X, N_NODES, F_IN, Wtp0, b0, zbuf, hn16, cs16);
    hipMemsetAsync(stats, 0, STB, stream);
    aggregate_w<<<AGB, 256, 0, stream>>>(hn16, row_ptr, esrc, cs16, pre16, stats);
    bn_apply16<<<1024, 256, 0, stream>>>(pre16, nullptr, hc, stats,
                                         bn_g, bn_b, N_NODES, TOT8, HDIM / 8);

    // ---- layers 1..3 (K = 128, residual in fp16, N-split)
    for (int l = 0; l < 3; l++) {
        gemm16_ns<<<GB, 256, 0, stream>>>(hc, N_NODES, Wtpl + (size_t)l * 32768,
                                          bvec + l * HDIM, hn16, cs16);
        hipMemsetAsync(stats, 0, STB, stream);
        aggregate_w<<<AGB, 256, 0, stream>>>(hn16, row_ptr, esrc, cs16, pre16, stats);
        bn_apply16<<<1024, 256, 0, stream>>>(pre16, hc, hx, stats,
                                             bn_g + (l + 1) * HDIM,
                                             bn_b + (l + 1) * HDIM, N_NODES,
                                             TOT8, HDIM / 8);
        _Float16* t = hc; hc = hx; hx = t;
    }

    // ---- MLP head (Z-stats fused into mlp_gemm; BN finalize in final_out)
    hipMemsetAsync(stats, 0, STB, stream);
    mlp_gemm<<<(N_NODES + 63) / 64, 256, 0, stream>>>(hc, W1, b1, Z, stats, N_NODES);
    final_out<<<AGB, 256, 0, stream>>>(Z, stats, bng1, bnb1, W2, b2,
                                       out, N_NODES);
}

// Round 7
// 1179.320 us; speedup vs baseline: 1.1335x; 1.0165x over previous
//
#include <hip/hip_runtime.h>
#include <hip/hip_bf16.h>

#define N_NODES 100000
#define N_EDGES 1600000
#define F_IN    700
#define NKB0    22          // ceil(700/32)
#define HDIM    128
#define SCAN_B  256
#define NB_SCAN ((N_NODES + SCAN_B - 1) / SCAN_B)   // 391
#define NSHARD  64          // stats shards: stats[NSHARD][256] (sum | sumsq@+128)

typedef _Float16 half8 __attribute__((ext_vector_type(8)));
typedef _Float16 half4 __attribute__((ext_vector_type(4)));
typedef float floatx4 __attribute__((ext_vector_type(4)));

// async global->LDS, 16B per lane; dst slot = wave-uniform base + lane*16
__device__ __forceinline__ void cp16(const void* g, void* l) {
    __builtin_amdgcn_global_load_lds(
        (const __attribute__((address_space(1))) void*)g,
        (__attribute__((address_space(3))) void*)l, 16, 0, 0);
}

// ---------------------------------------------------------------- CSR build
__global__ void count_edges(const int* __restrict__ graph, int* __restrict__ cnt) {
    int e = blockIdx.x * blockDim.x + threadIdx.x;
    if (e < N_EDGES) atomicAdd(&cnt[graph[2 * e + 1]], 1);
}

__global__ void scan1(const int* __restrict__ cnt, int* __restrict__ incl,
                      int* __restrict__ blk) {
    __shared__ int s[SCAN_B];
    int tid = threadIdx.x;
    int i = blockIdx.x * SCAN_B + tid;
    s[tid] = (i < N_NODES) ? cnt[i] : 0;
    __syncthreads();
    for (int off = 1; off < SCAN_B; off <<= 1) {
        int t = (tid >= off) ? s[tid - off] : 0;
        __syncthreads();
        s[tid] += t;
        __syncthreads();
    }
    if (i < N_NODES) incl[i] = s[tid];
    if (tid == SCAN_B - 1) blk[blockIdx.x] = s[tid];
}

__global__ void scan2(const int* __restrict__ blk, int* __restrict__ blkoff) {
    __shared__ int s[512];
    int tid = threadIdx.x;
    s[tid] = (tid < NB_SCAN) ? blk[tid] : 0;
    __syncthreads();
    for (int off = 1; off < 512; off <<= 1) {
        int t = (tid >= off) ? s[tid - off] : 0;
        __syncthreads();
        s[tid] += t;
        __syncthreads();
    }
    if (tid < NB_SCAN) blkoff[tid] = (tid == 0) ? 0 : s[tid - 1];
}

__global__ void scan3(const int* __restrict__ incl, const int* __restrict__ blkoff,
                      int* __restrict__ row_ptr) {
    int i = blockIdx.x * SCAN_B + threadIdx.x;
    if (i < N_NODES) {
        row_ptr[i + 1] = incl[i] + blkoff[i >> 8];
        if (i == 0) row_ptr[0] = 0;
    }
}

__global__ void fill_edges(const int* __restrict__ graph, const int* __restrict__ row_ptr,
                           int* __restrict__ cursor, int* __restrict__ esrc) {
    int e = blockIdx.x * blockDim.x + threadIdx.x;
    if (e < N_EDGES) {
        int src = graph[2 * e];
        int dst = graph[2 * e + 1];
        esrc[row_ptr[dst] + atomicAdd(&cursor[dst], 1)] = src;
    }
}

// ------------------- weight packs: tile-major, XOR-swizzled LDS image (fp16)
__global__ void build_wtp0(const float* __restrict__ Wn, const float* __restrict__ Ws,
                           _Float16* __restrict__ out) {
    int q = blockIdx.x * blockDim.x + threadIdx.x;
    if (q >= NKB0 * 256 * 4) return;
    int kb = q >> 10;
    int r  = (q >> 2) & 255;
    int cc = q & 3;
    int k0 = kb * 32 + (cc ^ ((r >> 1) & 3)) * 8;
    half8 v;
    #pragma unroll
    for (int e = 0; e < 8; e++) {
        int k = k0 + e;
        float f = 0.0f;
        if (k < F_IN) f = (r < 128) ? Wn[k * 128 + r] : Ws[k * 128 + (r - 128)];
        v[e] = (_Float16)f;
    }
    *(half8*)&out[(size_t)q * 8] = v;
}

__global__ void build_wtpl(const float* __restrict__ Wn, const float* __restrict__ Ws,
                           _Float16* __restrict__ out) {
    int q = blockIdx.x * blockDim.x + threadIdx.x;
    if (q >= 3 * 4 * 256 * 4) return;
    int l = q >> 12;
    int rem = q & 4095;
    int kb = rem >> 10;
    int r  = (rem >> 2) & 255;
    int cc = rem & 3;
    int k0 = kb * 32 + (cc ^ ((r >> 1) & 3)) * 8;
    half8 v;
    #pragma unroll
    for (int e = 0; e < 8; e++) {
        int k = k0 + e;
        float f = (r < 128) ? Wn[l * 16384 + k * 128 + r]
                            : Ws[l * 16384 + k * 128 + (r - 128)];
        v[e] = (_Float16)f;
    }
    *(half8*)&out[(size_t)q * 8] = v;
}

// ---- layer-0 GEMM, UN-SPLIT N: M128 x N256, 512 threads (8 waves, 2x4).
// A (fp32, 16KB) staged ONCE per M-tile per kb; B full 256-col image (16KB).
// LDS 32KB/buf, 64KB dbuf -> 2 blocks/CU (16 waves). Counted-vmcnt pipeline:
// 4 loads/lane/stage, vmcnt(4), never 0 in main loop.
__global__ __launch_bounds__(512) void gemm0_nu(
    const float* __restrict__ A, int M, int K,
    const _Float16* __restrict__ Wtp, const float* __restrict__ bias,
    const float* __restrict__ zbuf,
    _Float16* __restrict__ Cn, _Float16* __restrict__ Cs) {
    __shared__ char sbuf[2][32768];   // A fp32 [0,16384), B fp16 [16384,32768)

    int tid = threadIdx.x;
    int wave = tid >> 6, lane = tid & 63;
    int lm = lane & 15, quad = lane >> 4;
    int wm = wave >> 2, wn = wave & 3;      // 2x4 waves: 64 rows x 64 cols each
    long row0 = (long)blockIdx.x * 128;

    floatx4 acc[4][4] = {};

    auto stage = [&](int kb, char* buf) {
        // A: 1024 16B chunks (r 0..127, slot cc 0..7); slot cc holds chunk cc^(r&7)
        #pragma unroll
        for (int pass = 0; pass < 2; pass++) {
            int q = pass * 512 + tid;
            int r = q >> 3, cc = q & 7;
            int ccg = cc ^ (r & 7);
            long grow = row0 + r;
            if (grow >= M) grow = 0;        // clamp: uniform load count per wave
            int gk = kb * 32 + ccg * 4;
            const float* src = (gk + 4 <= K) ? (A + grow * (long)K + gk) : zbuf;
            cp16(src, buf + pass * 8192 + wave * 1024);
        }
        // B: full 16KB per kb (1024 chunks), linear (pre-swizzled at pack time)
        const _Float16* wsrc = Wtp + (size_t)kb * 8192;
        #pragma unroll
        for (int pass = 0; pass < 2; pass++) {
            cp16(wsrc + (size_t)(pass * 512 + tid) * 8,
                 buf + 16384 + pass * 8192 + wave * 1024);
        }
    };

    stage(0, sbuf[0]);   // 4 loads in flight; waited inside the loop

    for (int kb = 0; kb < NKB0; kb++) {
        int p = kb & 1;
        if (kb + 1 < NKB0) {
            stage(kb + 1, sbuf[p ^ 1]);
            asm volatile("s_waitcnt vmcnt(4)\n\ts_barrier" ::: "memory");
        } else {
            asm volatile("s_waitcnt vmcnt(0)\n\ts_barrier" ::: "memory");
        }

        const float* Af = (const float*)sbuf[p];
        const _Float16* Bf = (const _Float16*)(sbuf[p] + 16384);
        half8 af[4];
        #pragma unroll
        for (int i = 0; i < 4; i++) {
            int row = wm * 64 + i * 16 + lm;
            int c0 = (quad * 2) ^ (row & 7);
            int c1 = (quad * 2 + 1) ^ (row & 7);
            floatx4 f0 = *(const floatx4*)&Af[row * 32 + c0 * 4];
            floatx4 f1 = *(const floatx4*)&Af[row * 32 + c1 * 4];
            af[i][0] = (_Float16)f0[0]; af[i][1] = (_Float16)f0[1];
            af[i][2] = (_Float16)f0[2]; af[i][3] = (_Float16)f0[3];
            af[i][4] = (_Float16)f1[0]; af[i][5] = (_Float16)f1[1];
            af[i][6] = (_Float16)f1[2]; af[i][7] = (_Float16)f1[3];
        }
        #pragma unroll
        for (int j = 0; j < 4; j++) {
            int brow = wn * 64 + j * 16 + lm;           // B-pack row 0..255
            int ch = quad ^ ((brow >> 1) & 3);
            half8 bf = *(const half8*)&Bf[brow * 32 + ch * 8];
            #pragma unroll
            for (int i = 0; i < 4; i++)
                acc[i][j] = __builtin_amdgcn_mfma_f32_16x16x32_f16(af[i], bf, acc[i][j], 0, 0, 0);
        }
        asm volatile("s_waitcnt lgkmcnt(0)\n\ts_barrier" ::: "memory");
    }

    #pragma unroll
    for (int i = 0; i < 4; i++) {
        long r0 = row0 + wm * 64 + i * 16 + quad * 4;
        #pragma unroll
        for (int j = 0; j < 4; j++) {
            int c = wn * 64 + j * 16 + lm;              // 0..255: Cn | Cs
            if (c >= 128) {
                float badd = bias[c - 128];
                #pragma unroll
                for (int rr = 0; rr < 4; rr++) {
                    long r = r0 + rr;
                    if (r < M) Cs[r * HDIM + (c - 128)] = (_Float16)(acc[i][j][rr] + badd);
                }
            } else {
                #pragma unroll
                for (int rr = 0; rr < 4; rr++) {
                    long r = r0 + rr;
                    if (r < M) Cn[r * HDIM + c] = (_Float16)acc[i][j][rr];
                }
            }
        }
    }
}

// ---- K=128 GEMM, UN-SPLIT N: M128 x N256, 512 threads; fp16 A staged once.
// LDS 24KB/buf (A 8KB + B 16KB), 48KB dbuf. 3 loads/lane/stage -> vmcnt(3).
__global__ __launch_bounds__(512) void gemm16_nu(
    const _Float16* __restrict__ A, int M,
    const _Float16* __restrict__ Wtp, const float* __restrict__ bias,
    _Float16* __restrict__ Cn, _Float16* __restrict__ Cs) {
    __shared__ _Float16 sbuf[2][12288];  // A [0,4096), B [4096,12288) halves

    int tid = threadIdx.x;
    int wave = tid >> 6, lane = tid & 63;
    int lm = lane & 15, quad = lane >> 4;
    int wm = wave >> 2, wn = wave & 3;
    long row0 = (long)blockIdx.x * 128;

    floatx4 acc[4][4] = {};

    auto stage = [&](int kb, _Float16* buf) {
        {   // A: 512 chunks (r 0..127, slot cc 0..3), 1 cp16/thread
            int r = tid >> 2, cc = tid & 3;
            int ccg = cc ^ ((r >> 1) & 3);
            long grow = row0 + r;
            if (grow >= M) grow = 0;        // clamp: uniform load count per wave
            cp16(A + grow * (long)HDIM + kb * 32 + ccg * 8,
                 buf + wave * 512);
        }
        const _Float16* wsrc = Wtp + (size_t)kb * 8192;
        #pragma unroll
        for (int pass = 0; pass < 2; pass++) {
            cp16(wsrc + (size_t)(pass * 512 + tid) * 8,
                 buf + 4096 + pass * 4096 + wave * 512);
        }
    };

    stage(0, sbuf[0]);   // 3 loads in flight

    for (int kb = 0; kb < 4; kb++) {
        int p = kb & 1;
        if (kb + 1 < 4) {
            stage(kb + 1, sbuf[p ^ 1]);
            asm volatile("s_waitcnt vmcnt(3)\n\ts_barrier" ::: "memory");
        } else {
            asm volatile("s_waitcnt vmcnt(0)\n\ts_barrier" ::: "memory");
        }

        const _Float16* bp = sbuf[p];
        half8 af[4];
        #pragma unroll
        for (int i = 0; i < 4; i++) {
            int row = wm * 64 + i * 16 + lm;
            int ch = quad ^ ((row >> 1) & 3);
            af[i] = *(const half8*)&bp[row * 32 + ch * 8];
        }
        #pragma unroll
        for (int j = 0; j < 4; j++) {
            int brow = wn * 64 + j * 16 + lm;           // 0..255
            int ch = quad ^ ((brow >> 1) & 3);
            half8 bf = *(const half8*)&bp[4096 + brow * 32 + ch * 8];
            #pragma unroll
            for (int i = 0; i < 4; i++)
                acc[i][j] = __builtin_amdgcn_mfma_f32_16x16x32_f16(af[i], bf, acc[i][j], 0, 0, 0);
        }
        asm volatile("s_waitcnt lgkmcnt(0)\n\ts_barrier" ::: "memory");
    }

    #pragma unroll
    for (int i = 0; i < 4; i++) {
        long r0 = row0 + wm * 64 + i * 16 + quad * 4;
        #pragma unroll
        for (int j = 0; j < 4; j++) {
            int c = wn * 64 + j * 16 + lm;
            if (c >= 128) {
                float badd = bias[c - 128];
                #pragma unroll
                for (int rr = 0; rr < 4; rr++) {
                    long r = r0 + rr;
                    if (r < M) Cs[r * HDIM + (c - 128)] = (_Float16)(acc[i][j][rr] + badd);
                }
            } else {
                #pragma unroll
                for (int rr = 0; rr < 4; rr++) {
                    long r = r0 + rr;
                    if (r < M) Cn[r * HDIM + c] = (_Float16)acc[i][j][rr];
                }
            }
        }
    }
}

// --------------- aggregation + fused BN stats (stats[NSHARD][256], sharded)
__global__ __launch_bounds__(256) void aggregate_w(
    const _Float16* __restrict__ hn, const int* __restrict__ row_ptr,
    const int* __restrict__ esrc, const _Float16* __restrict__ cs16,
    _Float16* __restrict__ pre16, float* __restrict__ stats) {
    __shared__ float s1[4][HDIM], s2[4][HDIM];
    int tid = threadIdx.x;
    int wave = tid >> 6, lane = tid & 63;
    int n = blockIdx.x * 4 + wave;
    bool valid = (n < N_NODES);
    int eg = lane >> 4;            // edge slot 0..3
    int c8 = (lane & 15) * 8;      // channel group

    float pv[8] = {};              // final pre values (eg==0 lanes)
    if (valid) {
        int start = row_ptr[n], end = row_ptr[n + 1];
        float acc[8] = {};
        for (int base = start; base < end; base += 16) {
            #pragma unroll
            for (int u = 0; u < 4; u++) {
                int e = base + u * 4 + eg;
                if (e < end) {
                    int s = esrc[e];
                    half8 v = *(const half8*)&hn[(size_t)s * HDIM + c8];
                    #pragma unroll
                    for (int i = 0; i < 8; i++) acc[i] += (float)v[i];
                }
            }
        }
        #pragma unroll
        for (int i = 0; i < 8; i++) {
            acc[i] += __shfl_xor(acc[i], 16, 64);
            acc[i] += __shfl_xor(acc[i], 32, 64);
        }
        if (eg == 0) {
            float rd = 1.0f / (float)max(end - start, 1);
            half8 sv = *(const half8*)&cs16[(size_t)n * HDIM + c8];
            half8 h;
            #pragma unroll
            for (int i = 0; i < 8; i++) {
                pv[i] = acc[i] * rd + (float)sv[i];
                h[i] = (_Float16)pv[i];
            }
            *(half8*)&pre16[(size_t)n * HDIM + c8] = h;
        }
    }
    if (eg == 0) {
        #pragma unroll
        for (int i = 0; i < 8; i++) {
            float v = valid ? pv[i] : 0.0f;
            s1[wave][c8 + i] = v;
            s2[wave][c8 + i] = v * v;
        }
    }
    __syncthreads();
    if (tid < HDIM) {
        float a = s1[0][tid] + s1[1][tid] + s1[2][tid] + s1[3][tid];
        float b = s2[0][tid] + s2[1][tid] + s2[2][tid] + s2[3][tid];
        float* sh = stats + (size_t)(blockIdx.x & (NSHARD - 1)) * 256;
        atomicAdd(&sh[tid], a);
        atomicAdd(&sh[128 + tid], b);
    }
}

// h16 = fp16(relu(P*scale+shift [+ res16])); P fp16, 8-wide; stats from shards
__global__ void bn_apply16(const _Float16* __restrict__ P, const _Float16* __restrict__ res16,
                           _Float16* __restrict__ out16,
                           const float* __restrict__ stats,
                           const float* __restrict__ gamma, const float* __restrict__ beta,
                           int M, int total8, int Cdiv8) {
    __shared__ float ssc[HDIM], ssh[HDIM];
    int tid = threadIdx.x;
    int C = Cdiv8 * 8;
    if (tid < C) {
        float s = 0.0f, s2 = 0.0f;
        #pragma unroll 8
        for (int k = 0; k < NSHARD; k++) {
            s  += stats[k * 256 + tid];
            s2 += stats[k * 256 + 128 + tid];
        }
        float mean = s / (float)M;
        float var = s2 / (float)M - mean * mean;
        float sc = rsqrtf(var + 1e-5f) * gamma[tid];
        ssc[tid] = sc;
        ssh[tid] = beta[tid] - mean * sc;
    }
    __syncthreads();
    for (int f = blockIdx.x * blockDim.x + tid; f < total8;
         f += gridDim.x * blockDim.x) {
        int c8 = (f % Cdiv8) * 8;
        half8 v = *(const half8*)&P[(size_t)f * 8];
        half8 h;
        if (res16) {
            half8 rv = *(const half8*)&res16[(size_t)f * 8];
            #pragma unroll
            for (int i = 0; i < 8; i++) {
                float x = (float)v[i] * ssc[c8 + i] + ssh[c8 + i] + (float)rv[i];
                h[i] = (_Float16)fmaxf(x, 0.0f);
            }
        } else {
            #pragma unroll
            for (int i = 0; i < 8; i++) {
                float x = (float)v[i] * ssc[c8 + i] + ssh[c8 + i];
                h[i] = (_Float16)fmaxf(x, 0.0f);
            }
        }
        *(half8*)&out16[(size_t)f * 8] = h;
    }
}

// ------------------------- MLP head with fused Z-stats (sharded, C=64)
__global__ __launch_bounds__(256) void mlp_gemm(const _Float16* __restrict__ H,
                                                const float* __restrict__ W1,
                                                const float* __restrict__ b1,
                                                float* __restrict__ Z,
                                                float* __restrict__ stats, int M) {
    __shared__ float hs[64 * 132];
    __shared__ float ws[128 * 64];
    __shared__ float zs1[16][64], zs2[16][64];
    int tid = threadIdx.x;
    int tx = tid & 15;
    int ty = tid >> 4;
    int row0 = blockIdx.x * 64;

    #pragma unroll
    for (int t = 0; t < 8; t++) {
        int f = tid + t * 256;
        int r = f >> 4, c4 = (f & 15) * 4;
        *(float4*)&ws[r * 64 + c4] = *(const float4*)&W1[r * 64 + c4];
    }
    #pragma unroll
    for (int t = 0; t < 4; t++) {
        int f = tid + t * 256;
        int r = f >> 4, c8 = (f & 15) * 8;
        int gr = row0 + r;
        if (gr < M) {
            half8 hv = *(const half8*)&H[(size_t)gr * HDIM + c8];
            #pragma unroll
            for (int i = 0; i < 8; i++) hs[r * 132 + c8 + i] = (float)hv[i];
        } else {
            #pragma unroll
            for (int i = 0; i < 8; i++) hs[r * 132 + c8 + i] = 0.0f;
        }
    }
    __syncthreads();

    float acc[4][4] = {};
    for (int k = 0; k < 128; k++) {
        float a[4];
        #pragma unroll
        for (int i = 0; i < 4; i++) a[i] = hs[(ty * 4 + i) * 132 + k];
        float4 b4 = *(const float4*)&ws[k * 64 + tx * 4];
        #pragma unroll
        for (int i = 0; i < 4; i++) {
            acc[i][0] += a[i] * b4.x; acc[i][1] += a[i] * b4.y;
            acc[i][2] += a[i] * b4.z; acc[i][3] += a[i] * b4.w;
        }
    }
    float4 bb = *(const float4*)&b1[tx * 4];
    float cs[4] = {}, cq[4] = {};
    #pragma unroll
    for (int i = 0; i < 4; i++) {
        int r = row0 + ty * 4 + i;
        if (r < M) {
            float v0 = acc[i][0] + bb.x;
            float v1 = acc[i][1] + bb.y;
            float v2 = acc[i][2] + bb.z;
            float v3 = acc[i][3] + bb.w;
            float4 v = {v0, v1, v2, v3};
            *(float4*)&Z[(size_t)r * 64 + tx * 4] = v;
            cs[0] += v0; cq[0] += v0 * v0;
            cs[1] += v1; cq[1] += v1 * v1;
            cs[2] += v2; cq[2] += v2 * v2;
            cs[3] += v3; cq[3] += v3 * v3;
        }
    }
    #pragma unroll
    for (int j = 0; j < 4; j++) {
        zs1[ty][tx * 4 + j] = cs[j];
        zs2[ty][tx * 4 + j] = cq[j];
    }
    __syncthreads();
    if (tid < 64) {
        float a = 0.0f, b = 0.0f;
        #pragma unroll
        for (int k = 0; k < 16; k++) { a += zs1[k][tid]; b += zs2[k][tid]; }
        float* sh = stats + (size_t)(blockIdx.x & (NSHARD - 1)) * 256;
        atomicAdd(&sh[tid], a);
        atomicAdd(&sh[128 + tid], b);
    }
}

// out[n] = relu(bn(Z[n,:])) . W2 + b2  — BN finalize+apply fused into the dot
__global__ void final_out(const float* __restrict__ Z,
                          const float* __restrict__ stats,
                          const float* __restrict__ gamma, const float* __restrict__ beta,
                          const float* __restrict__ W2, const float* __restrict__ b2,
                          float* __restrict__ out, int M) {
    __shared__ float ssc[64], ssh[64], sw[64];
    int tid = threadIdx.x;
    if (tid < 64) {
        float s = 0.0f, s2 = 0.0f;
        #pragma unroll 8
        for (int k = 0; k < NSHARD; k++) {
            s  += stats[k * 256 + tid];
            s2 += stats[k * 256 + 128 + tid];
        }
        float mean = s / (float)M;
        float var = s2 / (float)M - mean * mean;
        float sc = rsqrtf(var + 1e-5f) * gamma[tid];
        ssc[tid] = sc;
        ssh[tid] = beta[tid] - mean * sc;
        sw[tid] = W2[tid];
    }
    __syncthreads();
    int n = blockIdx.x * 4 + (tid >> 6);
    int lane = tid & 63;
    if (n >= N_NODES) return;
    float z = Z[(size_t)n * 64 + lane] * ssc[lane] + ssh[lane];
    z = fmaxf(z, 0.0f);
    float v = z * sw[lane];
    #pragma unroll
    for (int off = 32; off >= 1; off >>= 1) v += __shfl_down(v, off, 64);
    if (lane == 0) out[n] = v + b2[0];
}

// ------------------------------------------------------------------ driver
extern "C" void kernel_launch(void* const* d_in, const int* in_sizes, int n_in,
                              void* d_out, int out_size, void* d_ws, size_t ws_size,
                              hipStream_t stream) {
    const float* X       = (const float*)d_in[0];
    const int*   graph   = (const int*)d_in[1];
    const float* Wself0  = (const float*)d_in[2];
    const float* Wneigh0 = (const float*)d_in[3];
    const float* b0      = (const float*)d_in[4];
    const float* Wself   = (const float*)d_in[5];
    const float* Wneigh  = (const float*)d_in[6];
    const float* bvec    = (const float*)d_in[7];
    const float* bn_g    = (const float*)d_in[8];
    const float* bn_b    = (const float*)d_in[9];
    const float* W1      = (const float*)d_in[10];
    const float* b1      = (const float*)d_in[11];
    const float* bng1    = (const float*)d_in[12];
    const float* bnb1    = (const float*)d_in[13];
    const float* W2      = (const float*)d_in[14];
    const float* b2      = (const float*)d_in[15];
    float* out = (float*)d_out;

    size_t off = 0;
    auto alloc = [&](size_t bytes) {
        void* p = (char*)d_ws + off;
        off += (bytes + 255) & ~(size_t)255;
        return p;
    };
    int* cnt     = (int*)alloc(N_NODES * 4);
    int* cursor  = (int*)alloc(N_NODES * 4);
    int* row_ptr = (int*)alloc((N_NODES + 1) * 4);
    int* incl    = (int*)alloc(N_NODES * 4);
    int* blk     = (int*)alloc(NB_SCAN * 4);
    int* blkoff  = (int*)alloc(NB_SCAN * 4);
    int* esrc    = (int*)alloc((size_t)N_EDGES * 4);
    _Float16* pre16 = (_Float16*)alloc((size_t)N_NODES * HDIM * 2); // 25.6 MB
    _Float16* cs16  = (_Float16*)alloc((size_t)N_NODES * HDIM * 2); // 25.6 MB
    _Float16* h16A  = (_Float16*)alloc((size_t)N_NODES * HDIM * 2); // 25.6 MB
    _Float16* h16B  = (_Float16*)alloc((size_t)N_NODES * HDIM * 2);
    _Float16* hn16  = (_Float16*)alloc((size_t)N_NODES * HDIM * 2);
    float*    Z     = (float*)alloc((size_t)N_NODES * 64 * 4);
    _Float16* Wtp0  = (_Float16*)alloc((size_t)NKB0 * 8192 * 2);
    _Float16* Wtpl  = (_Float16*)alloc((size_t)3 * 4 * 8192 * 2);
    float*    zbuf  = (float*)alloc(256);
    float*    stats = (float*)alloc((size_t)NSHARD * 256 * 4);      // 64 KB

    const int EB = (N_EDGES + 255) / 256;
    const int GB2 = (N_NODES + 127) / 128;        // 782 (un-split N)
    const int AGB = (N_NODES + 3) / 4;            // 25000
    const size_t STB = (size_t)NSHARD * 256 * 4;
    const int TOT8 = N_NODES * HDIM / 8;

    // CSR build
    hipMemsetAsync(cnt, 0, N_NODES * 4, stream);
    hipMemsetAsync(cursor, 0, N_NODES * 4, stream);
    hipMemsetAsync(zbuf, 0, 256, stream);
    count_edges<<<EB, 256, 0, stream>>>(graph, cnt);
    scan1<<<NB_SCAN, SCAN_B, 0, stream>>>(cnt, incl, blk);
    scan2<<<1, 512, 0, stream>>>(blk, blkoff);
    scan3<<<NB_SCAN, SCAN_B, 0, stream>>>(incl, blkoff, row_ptr);
    fill_edges<<<EB, 256, 0, stream>>>(graph, row_ptr, cursor, esrc);

    // weight packs
    build_wtp0<<<(NKB0 * 1024 + 255) / 256, 256, 0, stream>>>(Wneigh0, Wself0, Wtp0);
    build_wtpl<<<(3 * 4096 + 255) / 256, 256, 0, stream>>>(Wneigh, Wself, Wtpl);

    _Float16* hc = h16A;
    _Float16* hx = h16B;

    // ---- layer 0 (K = 700, fp32 A direct, un-split N)
    gemm0_nu<<<GB2, 512, 0, stream>>>(X, N_NODES, F_IN, Wtp0, b0, zbuf, hn16, cs16);
    hipMemsetAsync(stats, 0, STB, stream);
    aggregate_w<<<AGB, 256, 0, stream>>>(hn16, row_ptr, esrc, cs16, pre16, stats);
    bn_apply16<<<1024, 256, 0, stream>>>(pre16, nullptr, hc, stats,
                                         bn_g, bn_b, N_NODES, TOT8, HDIM / 8);

    // ---- layers 1..3 (K = 128, residual in fp16, un-split N)
    for (int l = 0; l < 3; l++) {
        gemm16_nu<<<GB2, 512, 0, stream>>>(hc, N_NODES, Wtpl + (size_t)l * 32768,
                                           bvec + l * HDIM, hn16, cs16);
        hipMemsetAsync(stats, 0, STB, stream);
        aggregate_w<<<AGB, 256, 0, stream>>>(hn16, row_ptr, esrc, cs16, pre16, stats);
        bn_apply16<<<1024, 256, 0, stream>>>(pre16, hc, hx, stats,
                                             bn_g + (l + 1) * HDIM,
                                             bn_b + (l + 1) * HDIM, N_NODES,
                                             TOT8, HDIM / 8);
        _Float16* t = hc; hc = hx; hx = t;
    }

    // ---- MLP head (Z-stats fused into mlp_gemm; BN finalize in final_out)
    hipMemsetAsync(stats, 0, STB, stream);
    mlp_gemm<<<(N_NODES + 63) / 64, 256, 0, stream>>>(hc, W1, b1, Z, stats, N_NODES);
    final_out<<<AGB, 256, 0, stream>>>(Z, stats, bng1, bnb1, W2, b2,
                                       out, N_NODES);
}